// Round 1
// baseline (5397.730 us; speedup 1.0000x reference)
//
#include <hip/hip_runtime.h>
#include <hip/hip_bf16.h>
#include <math.h>

// Problem constants (from reference): B=1024, L=32, D=256, H=8, hd=32, STATE=16
static constexpr int Bsz  = 1024;
static constexpr int Lseq = 32;
static constexpr int Dm   = 256;
static constexpr int NROW = Bsz * Lseq;   // 32768

__device__ __forceinline__ float gelu_f(float x) {
    // exact gelu: x * 0.5 * (1 + erf(x/sqrt(2)))
    return 0.5f * x * (1.0f + erff(x * 0.7071067811865475f));
}

// ---------------------------------------------------------------------------
// Generic fp32 GEMM: C[n,m] = epi(act(X @ W^T + b1 (+ b2)))  (+= C if ACCUM)
// X: (N,K) row-major, W: (M,K) row-major (torch linear layout).
// ACT: 0 none, 1 sigmoid, 2 gelu. EPI: 0 none, 1 mul E[n,m], 2 add E[n,m].
// Tile 64x64, BK=32, 256 threads, 4x4 micro-tile. N,M % 64 == 0, K % 32 == 0.
// ---------------------------------------------------------------------------
template<int ACT, int EPI, bool ACCUM>
__global__ __launch_bounds__(256)
void gemm_k(const float* __restrict__ X, const float* __restrict__ W,
            const float* __restrict__ b1, const float* __restrict__ b2,
            const float* __restrict__ E, float* __restrict__ C,
            int K, int M)
{
    __shared__ float Xs[32][68];   // k-major, +4 pad keeps 16B align & spreads banks
    __shared__ float Ws[32][68];
    const int tid = threadIdx.x;
    const int n0 = blockIdx.y << 6;
    const int m0 = blockIdx.x << 6;
    const int tr = tid >> 4, tc = tid & 15;
    const int lr = tid >> 3;             // 0..31
    const int lc = (tid & 7) << 2;       // 0,4,..,28
    float acc[4][4] = {};
    const float* Xp0 = X + (size_t)(n0 + lr) * K + lc;
    const float* Xp1 = X + (size_t)(n0 + lr + 32) * K + lc;
    const float* Wp0 = W + (size_t)(m0 + lr) * K + lc;
    const float* Wp1 = W + (size_t)(m0 + lr + 32) * K + lc;

    for (int kc = 0; kc < K; kc += 32) {
        const float4 x0 = *reinterpret_cast<const float4*>(Xp0 + kc);
        const float4 x1 = *reinterpret_cast<const float4*>(Xp1 + kc);
        const float4 w0 = *reinterpret_cast<const float4*>(Wp0 + kc);
        const float4 w1 = *reinterpret_cast<const float4*>(Wp1 + kc);
        Xs[lc+0][lr]    = x0.x; Xs[lc+1][lr]    = x0.y; Xs[lc+2][lr]    = x0.z; Xs[lc+3][lr]    = x0.w;
        Xs[lc+0][lr+32] = x1.x; Xs[lc+1][lr+32] = x1.y; Xs[lc+2][lr+32] = x1.z; Xs[lc+3][lr+32] = x1.w;
        Ws[lc+0][lr]    = w0.x; Ws[lc+1][lr]    = w0.y; Ws[lc+2][lr]    = w0.z; Ws[lc+3][lr]    = w0.w;
        Ws[lc+0][lr+32] = w1.x; Ws[lc+1][lr+32] = w1.y; Ws[lc+2][lr+32] = w1.z; Ws[lc+3][lr+32] = w1.w;
        __syncthreads();
        #pragma unroll
        for (int kk = 0; kk < 32; ++kk) {
            const float4 a4 = *reinterpret_cast<const float4*>(&Xs[kk][tr << 2]);
            const float4 b4 = *reinterpret_cast<const float4*>(&Ws[kk][tc << 2]);
            const float av[4] = {a4.x, a4.y, a4.z, a4.w};
            const float bv[4] = {b4.x, b4.y, b4.z, b4.w};
            #pragma unroll
            for (int i = 0; i < 4; ++i)
                #pragma unroll
                for (int j = 0; j < 4; ++j)
                    acc[i][j] = fmaf(av[i], bv[j], acc[i][j]);
        }
        __syncthreads();
    }

    const int cb = tc << 2;
    #pragma unroll
    for (int i = 0; i < 4; ++i) {
        const size_t row  = (size_t)(n0 + (tr << 2) + i);
        const size_t cidx = row * (size_t)M + m0 + cb;
        float v4[4];
        #pragma unroll
        for (int j = 0; j < 4; ++j) {
            const int col = m0 + cb + j;
            float v = acc[i][j] + b1[col];
            if (b2 != nullptr) v += b2[col];
            if (ACT == 1) v = 1.0f / (1.0f + expf(-v));
            else if (ACT == 2) v = gelu_f(v);
            if (EPI == 1) v *= E[cidx + j];
            else if (EPI == 2) v += E[cidx + j];
            v4[j] = v;
        }
        float4 o = make_float4(v4[0], v4[1], v4[2], v4[3]);
        if (ACCUM) {
            const float4 c = *reinterpret_cast<const float4*>(&C[cidx]);
            o.x += c.x; o.y += c.y; o.z += c.z; o.w += c.w;
        }
        *reinterpret_cast<float4*>(&C[cidx]) = o;
    }
}

// ---------------------------------------------------------------------------
// Row LayerNorm over D=256. One wave (64 lanes) per row, 4 rows per block.
// addOut: 0 -> Y = ln(X), 1 -> Y += ln(X). In-place (Y==X, addOut=0) is safe.
// ---------------------------------------------------------------------------
__global__ __launch_bounds__(256)
void ln_k(const float* __restrict__ X, const float* __restrict__ g,
          const float* __restrict__ bt, float* __restrict__ Y, int addOut)
{
    const int lane = threadIdx.x & 63;
    const int row  = (blockIdx.x << 2) + (threadIdx.x >> 6);
    const size_t base = (size_t)row * Dm + (lane << 2);
    float4 v = *reinterpret_cast<const float4*>(&X[base]);
    float s = v.x + v.y + v.z + v.w;
    #pragma unroll
    for (int o = 1; o < 64; o <<= 1) s += __shfl_xor(s, o);
    const float mu = s * (1.0f / 256.0f);
    const float d0 = v.x - mu, d1 = v.y - mu, d2 = v.z - mu, d3 = v.w - mu;
    float q = d0*d0 + d1*d1 + d2*d2 + d3*d3;
    #pragma unroll
    for (int o = 1; o < 64; o <<= 1) q += __shfl_xor(q, o);
    const float rstd = rsqrtf(q * (1.0f / 256.0f) + 1e-5f);
    const int c = lane << 2;
    const float4 gg = *reinterpret_cast<const float4*>(&g[c]);
    const float4 bb = *reinterpret_cast<const float4*>(&bt[c]);
    float4 o4 = make_float4(d0*rstd*gg.x + bb.x, d1*rstd*gg.y + bb.y,
                            d2*rstd*gg.z + bb.z, d3*rstd*gg.w + bb.w);
    if (addOut) {
        const float4 y = *reinterpret_cast<const float4*>(&Y[base]);
        o4.x += y.x; o4.y += y.y; o4.z += y.z; o4.w += y.w;
    }
    *reinterpret_cast<float4*>(&Y[base]) = o4;
}

// ---------------------------------------------------------------------------
// Cross-attention core for one (batch, head): 32x32 Q,K,V tiles (hd=32).
// O[b,q,h*32+d] = softmax(Q K^T / sqrt(32)) V.  Grid = B*H, 256 threads.
// Softmax-weight means are analytically 1/32 (rows sum to 1) -> not computed.
// ---------------------------------------------------------------------------
__global__ __launch_bounds__(256)
void attn_k(const float* __restrict__ Q, const float* __restrict__ K,
            const float* __restrict__ V, float* __restrict__ O)
{
    __shared__ float Qs[32][33], Ks[32][33], Vs[32][33], Ss[32][33];
    const int bh = blockIdx.x;
    const int b = bh >> 3, h = bh & 7;
    const int tid = threadIdx.x;
    const int r  = tid >> 3;            // 0..31 (row)
    const int c4 = (tid & 7) << 2;      // 0,4,..,28
    const size_t base = ((size_t)b * Lseq + r) * Dm + h * 32 + c4;
    {
        const float4 q = *reinterpret_cast<const float4*>(&Q[base]);
        Qs[r][c4+0]=q.x; Qs[r][c4+1]=q.y; Qs[r][c4+2]=q.z; Qs[r][c4+3]=q.w;
        const float4 k = *reinterpret_cast<const float4*>(&K[base]);
        Ks[r][c4+0]=k.x; Ks[r][c4+1]=k.y; Ks[r][c4+2]=k.z; Ks[r][c4+3]=k.w;
        const float4 v = *reinterpret_cast<const float4*>(&V[base]);
        Vs[r][c4+0]=v.x; Vs[r][c4+1]=v.y; Vs[r][c4+2]=v.z; Vs[r][c4+3]=v.w;
    }
    __syncthreads();
    float sc[4] = {0.f, 0.f, 0.f, 0.f};
    #pragma unroll
    for (int d = 0; d < 32; ++d) {
        const float qv = Qs[r][d];
        #pragma unroll
        for (int j = 0; j < 4; ++j) sc[j] = fmaf(qv, Ks[c4+j][d], sc[j]);
    }
    #pragma unroll
    for (int j = 0; j < 4; ++j) sc[j] *= 0.17677669529663687f;  // 1/sqrt(32)
    float mx = fmaxf(fmaxf(sc[0], sc[1]), fmaxf(sc[2], sc[3]));
    #pragma unroll
    for (int o = 1; o < 8; o <<= 1) mx = fmaxf(mx, __shfl_xor(mx, o));
    float sum = 0.f;
    #pragma unroll
    for (int j = 0; j < 4; ++j) { sc[j] = expf(sc[j] - mx); sum += sc[j]; }
    #pragma unroll
    for (int o = 1; o < 8; o <<= 1) sum += __shfl_xor(sum, o);
    const float inv = 1.0f / sum;
    #pragma unroll
    for (int j = 0; j < 4; ++j) Ss[r][c4+j] = sc[j] * inv;
    __syncthreads();
    float o4[4] = {0.f, 0.f, 0.f, 0.f};
    #pragma unroll
    for (int k = 0; k < 32; ++k) {
        const float wv = Ss[r][k];
        #pragma unroll
        for (int j = 0; j < 4; ++j) o4[j] = fmaf(wv, Vs[k][c4+j], o4[j]);
    }
    *reinterpret_cast<float4*>(&O[base]) = make_float4(o4[0], o4[1], o4[2], o4[3]);
}

// ---------------------------------------------------------------------------
// SSM scan for one batch: h_t = h_{t-1} A^T + x_t B^T ; y_t = h_t C^T.
// Block per batch (1024 blocks, 256 threads). x (32x256) staged in LDS,
// xB[t][s] precomputed in parallel, then 32 sequential steps (16-wide h).
// ---------------------------------------------------------------------------
__global__ __launch_bounds__(256)
void scan_k(const float* __restrict__ Xin, const float* __restrict__ A,
            const float* __restrict__ Bm, const float* __restrict__ Cc,
            float* __restrict__ Ys)
{
    __shared__ float xs[32 * 256];      // 32 KB
    __shared__ float Cs[256][17];       // padded: y-read bank spread
    __shared__ float As[256];
    __shared__ float xB[32][16];
    __shared__ float hbuf[2][16];
    const int tid = threadIdx.x;
    const size_t base = (size_t)blockIdx.x * (Lseq * Dm);
    #pragma unroll
    for (int i = 0; i < 8; ++i) {
        const int f = (i << 8) + tid;   // float4 index 0..2047
        *reinterpret_cast<float4*>(&xs[f << 2]) =
            *reinterpret_cast<const float4*>(&Xin[base + ((size_t)f << 2)]);
    }
    {
        const float4* cp = reinterpret_cast<const float4*>(&Cc[tid << 4]);
        #pragma unroll
        for (int i = 0; i < 4; ++i) {
            const float4 cv = cp[i];
            Cs[tid][(i<<2)+0] = cv.x; Cs[tid][(i<<2)+1] = cv.y;
            Cs[tid][(i<<2)+2] = cv.z; Cs[tid][(i<<2)+3] = cv.w;
        }
    }
    As[tid] = A[tid];
    if (tid < 32) hbuf[tid >> 4][tid & 15] = 0.0f;
    __syncthreads();
    #pragma unroll
    for (int rep = 0; rep < 2; ++rep) {
        const int task = tid + (rep << 8);         // 0..511
        const int tt = task >> 4, s = task & 15;
        const float* br = Bm + (s << 8);           // Bm row s (L1/L2 resident)
        const float* xr = xs + (tt << 8);
        float acc = 0.0f;
        #pragma unroll 8
        for (int d = 0; d < 256; ++d) acc = fmaf(xr[d], br[d], acc);
        xB[tt][s] = acc;
    }
    __syncthreads();
    for (int t = 0; t < 32; ++t) {
        const float* hp = hbuf[t & 1];
        float* hn = hbuf[(t & 1) ^ 1];
        if (tid < 16) {
            float acc = xB[t][tid];
            const float* ar = As + (tid << 4);
            #pragma unroll
            for (int s = 0; s < 16; ++s) acc = fmaf(ar[s], hp[s], acc);
            hn[tid] = acc;
        }
        __syncthreads();
        float acc = 0.0f;
        #pragma unroll
        for (int s = 0; s < 16; ++s) acc = fmaf(hn[s], Cs[tid][s], acc);
        Ys[base + (t << 8) + tid] = acc;
        // no trailing barrier needed: next step writes the OTHER h buffer, and
        // the barrier after the next h-update orders overwrites of this one.
    }
}

// mean over L: G[b,d] = mean_t X[b,t,d]
__global__ __launch_bounds__(256)
void meanL_k(const float* __restrict__ X, float* __restrict__ G)
{
    const int idx = blockIdx.x * 256 + threadIdx.x;
    const int b = idx >> 8, d = idx & 255;
    const float* xp = X + (size_t)b * (Lseq * Dm) + d;
    float s = 0.0f;
    #pragma unroll
    for (int t = 0; t < Lseq; ++t) s += xp[t << 8];
    G[idx] = s * (1.0f / 32.0f);
}

// softmax rows sum to 1 => wb = wv = 1/32 exactly (to f32 rounding)
__global__ __launch_bounds__(256)
void fillw_k(float* __restrict__ out)
{
    const int i = blockIdx.x * 256 + threadIdx.x;   // 0..2047
    const float wm = 1.0f / 32.0f;
    out[i] = wm / (wm + wm + 1e-6f);
}

extern "C" void kernel_launch(void* const* d_in, const int* in_sizes, int n_in,
                              void* d_out, int out_size, void* d_ws, size_t ws_size,
                              hipStream_t stream)
{
    // Inputs in setup_inputs() dict order:
    const float* ble_f   = (const float*)d_in[0];
    const float* vis_f   = (const float*)d_in[1];
    const float* bp_w    = (const float*)d_in[2];
    const float* bp_b    = (const float*)d_in[3];
    const float* bp_emb  = (const float*)d_in[4];
    const float* bp_g    = (const float*)d_in[5];
    const float* bp_beta = (const float*)d_in[6];
    const float* vp_w    = (const float*)d_in[7];
    const float* vp_b    = (const float*)d_in[8];
    const float* vp_emb  = (const float*)d_in[9];
    const float* vp_g    = (const float*)d_in[10];
    const float* vp_beta = (const float*)d_in[11];
    const float* a_qw    = (const float*)d_in[12];
    const float* a_qb    = (const float*)d_in[13];
    const float* a_kw    = (const float*)d_in[14];
    const float* a_kb    = (const float*)d_in[15];
    const float* a_vw    = (const float*)d_in[16];
    const float* a_vb    = (const float*)d_in[17];
    const float* a_ow    = (const float*)d_in[18];
    const float* a_ob    = (const float*)d_in[19];
    const float* a_g     = (const float*)d_in[20];
    const float* a_beta  = (const float*)d_in[21];
    const float* m_ln1_g = (const float*)d_in[22];
    const float* m_ln1_b = (const float*)d_in[23];
    const float* m_in_w  = (const float*)d_in[24];
    const float* m_in_b  = (const float*)d_in[25];
    const float* m_A     = (const float*)d_in[26];
    const float* m_B     = (const float*)d_in[27];
    const float* m_C     = (const float*)d_in[28];
    const float* m_gw    = (const float*)d_in[29];
    const float* m_gb    = (const float*)d_in[30];
    const float* m_sw    = (const float*)d_in[31];
    const float* m_sb    = (const float*)d_in[32];
    const float* m_ln2_g = (const float*)d_in[33];
    const float* m_ln2_b = (const float*)d_in[34];
    const float* m_f1w   = (const float*)d_in[35];
    const float* m_f1b   = (const float*)d_in[36];
    const float* m_f2w   = (const float*)d_in[37];
    const float* m_f2b   = (const float*)d_in[38];
    const float* fin_g   = (const float*)d_in[39];
    const float* fin_beta= (const float*)d_in[40];
    const float* fin_w   = (const float*)d_in[41];
    const float* fin_b   = (const float*)d_in[42];

    float* out = (float*)d_out;
    float* ws  = (float*)d_ws;
    const size_t NDf = (size_t)NROW * Dm;   // 8.4M floats
    // Workspace layout (7 * N*D f32 = 224 MiB):
    float* P6 = ws;            // fused / residual stream
    float* P0 = ws + 1*NDf;    // ble (then ln1/ln2 out, then mean-pool out)
    float* P1 = ws + 2*NDf;    // vis (then x_in)
    float* P2 = ws + 3*NDf;    // Q / gate / pre-LN attn out
    float* P3 = ws + 4*NDf;    // K / ys
    float* P4 = ws + 5*NDf;    // V
    float* P5 = ws + 6*NDf;    // attn core out
    float* S4 = P2;            // N x 1024 FFN hidden (spans P2..P5)

    const dim3 blk(256);
    auto gg = [](int M, int N) { return dim3(M / 64, N / 64); };

    // ---- input projections + LN ----
    gemm_k<0,0,false><<<gg(256, NROW), blk, 0, stream>>>(ble_f, bp_w, bp_b, bp_emb, nullptr, P0, 128, 256);
    ln_k<<<NROW/4, blk, 0, stream>>>(P0, bp_g, bp_beta, P0, 0);
    gemm_k<0,0,false><<<gg(256, NROW), blk, 0, stream>>>(vis_f, vp_w, vp_b, vp_emb, nullptr, P1, 256, 256);
    ln_k<<<NROW/4, blk, 0, stream>>>(P1, vp_g, vp_beta, P1, 0);

    // ---- two cross-attentions; fused accumulates into P6 ----
    for (int a = 0; a < 2; ++a) {
        const float* qin = (a == 0) ? P0 : P1;
        const float* kin = (a == 0) ? P1 : P0;
        const size_t wo = (size_t)a * 256 * 256;
        const size_t bo = (size_t)a * 256;
        gemm_k<0,0,false><<<gg(256, NROW), blk, 0, stream>>>(qin, a_qw + wo, a_qb + bo, nullptr, nullptr, P2, 256, 256);
        gemm_k<0,0,false><<<gg(256, NROW), blk, 0, stream>>>(kin, a_kw + wo, a_kb + bo, nullptr, nullptr, P3, 256, 256);
        gemm_k<0,0,false><<<gg(256, NROW), blk, 0, stream>>>(kin, a_vw + wo, a_vb + bo, nullptr, nullptr, P4, 256, 256);
        attn_k<<<Bsz * 8, blk, 0, stream>>>(P2, P3, P4, P5);
        // O-projection + residual(q_in), then LN -> P6 (store for a=0, add for a=1)
        gemm_k<0,2,false><<<gg(256, NROW), blk, 0, stream>>>(P5, a_ow + wo, a_ob + bo, nullptr, qin, P2, 256, 256);
        ln_k<<<NROW/4, blk, 0, stream>>>(P2, a_g + bo, a_beta + bo, P6, a);
    }

    // ---- 6 mamba blocks ----
    for (int i = 0; i < 6; ++i) {
        const float* ln1g = m_ln1_g + i*256;
        const float* ln1b = m_ln1_b + i*256;
        const float* inw2 = m_in_w + (size_t)i*512*256 + 256*256;  // rows D..2D-1 only
        const float* inb2 = m_in_b + (size_t)i*512 + 256;
        const float* Ai   = m_A + (size_t)i*256;
        const float* Bi   = m_B + (size_t)i*16*256;
        const float* Ci   = m_C + (size_t)i*256*16;
        const float* gwi  = m_gw + (size_t)i*256*256;
        const float* gbi  = m_gb + (size_t)i*256;
        const float* swi  = m_sw + (size_t)i*256*256;
        const float* sbi  = m_sb + (size_t)i*256;
        const float* ln2g = m_ln2_g + i*256;
        const float* ln2b = m_ln2_b + i*256;
        const float* f1w  = m_f1w + (size_t)i*1024*256;
        const float* f1b  = m_f1b + (size_t)i*1024;
        const float* f2w  = m_f2w + (size_t)i*256*1024;
        const float* f2b  = m_f2b + (size_t)i*256;

        ln_k<<<NROW/4, blk, 0, stream>>>(P6, ln1g, ln1b, P0, 0);
        // gate = sigmoid(xn @ gw^T + gb)
        gemm_k<1,0,false><<<gg(256, NROW), blk, 0, stream>>>(P0, gwi, gbi, nullptr, nullptr, P2, 256, 256);
        // x_in = (xn @ inw2^T + inb2) * gate
        gemm_k<0,1,false><<<gg(256, NROW), blk, 0, stream>>>(P0, inw2, inb2, nullptr, P2, P1, 256, 256);
        scan_k<<<Bsz, blk, 0, stream>>>(P1, Ai, Bi, Ci, P3);
        // fused += ys @ sw^T + sb
        gemm_k<0,0,true><<<gg(256, NROW), blk, 0, stream>>>(P3, swi, sbi, nullptr, nullptr, P6, 256, 256);
        // FFN
        ln_k<<<NROW/4, blk, 0, stream>>>(P6, ln2g, ln2b, P0, 0);
        gemm_k<2,0,false><<<gg(1024, NROW), blk, 0, stream>>>(P0, f1w, f1b, nullptr, nullptr, S4, 256, 1024);
        gemm_k<0,0,true><<<gg(256, NROW), blk, 0, stream>>>(S4, f2w, f2b, nullptr, nullptr, P6, 1024, 256);
    }

    // ---- head ----
    meanL_k<<<(Bsz * Dm) / 256, blk, 0, stream>>>(P6, P0);
    ln_k<<<Bsz/4, blk, 0, stream>>>(P0, fin_g, fin_beta, P0, 0);
    gemm_k<2,0,false><<<gg(256, Bsz), blk, 0, stream>>>(P0, fin_w, fin_b, nullptr, nullptr, out, 256, 256);
    fillw_k<<<8, blk, 0, stream>>>(out + (size_t)Bsz * Dm);
}

// Round 2
// 1815.561 us; speedup vs baseline: 2.9730x; 2.9730x over previous
//
#include <hip/hip_runtime.h>
#include <hip/hip_bf16.h>
#include <math.h>

static constexpr int Bsz  = 1024;
static constexpr int Lseq = 32;
static constexpr int Dm   = 256;
static constexpr int NROW = Bsz * Lseq;   // 32768

typedef __attribute__((ext_vector_type(8))) short bf16x8;
typedef __attribute__((ext_vector_type(4))) float f32x4;

__device__ __forceinline__ float gelu_f(float x) {
    return 0.5f * x * (1.0f + erff(x * 0.7071067811865475f));
}
__device__ __forceinline__ float b2f(ushort u) {
    union { float f; uint v; } t; t.v = ((uint)u) << 16; return t.f;
}
__device__ __forceinline__ ushort f2b(float f) {
    union { float f; uint v; } t; t.f = f;
    const uint lsb = (t.v >> 16) & 1u;
    t.v += 0x7fffu + lsb;                 // round-to-nearest-even
    return (ushort)(t.v >> 16);
}

#define GLDS(gp, lp) __builtin_amdgcn_global_load_lds( \
    (const __attribute__((address_space(1))) void*)(gp), \
    (__attribute__((address_space(3))) void*)(lp), 16, 0, 0)

// ---------------------------------------------------------------------------
// bf16 MFMA GEMM (m97 structure): C[n,m] = epi(act(X @ W^T + b1 (+b2)))
// X: (N,K) bf16 row-major, W: (M,K) bf16 row-major. Output fp32 or bf16.
// Tile 128x128, BK=32, 256 threads (4 waves, each 64x64 out).
// LDS tiles row-major [128][32] bf16 with 16B-slot swizzle slot^=((row>>1)&3),
// applied on BOTH the (pre-swizzled) global source of global_load_lds and the
// ds_read side -> 2-way bank aliasing (free). N%128==0, M%128==0, K%32==0.
// ACT: 0 none,1 sigmoid,2 gelu.  EPI: 0 none,1 mul E,2 add E (E fp32).
// ---------------------------------------------------------------------------
template<int ACT, int EPI, bool ACCUM, bool OUTBF>
__global__ __launch_bounds__(256)
void mgemm(const ushort* __restrict__ X, const ushort* __restrict__ W,
           const float* __restrict__ b1, const float* __restrict__ b2,
           const float* __restrict__ E, float* __restrict__ Cf,
           ushort* __restrict__ Cb, int K, int M)
{
    __shared__ ushort As[128 * 32];
    __shared__ ushort Bs[128 * 32];
    const int tid = threadIdx.x;
    const int w = tid >> 6, l = tid & 63;
    const int n0 = blockIdx.y << 7;
    const int m0 = blockIdx.x << 7;

    // ---- staging addresses (chunks w and w+4; 16 rows x 32 cols per chunk) ----
    const int ric  = l >> 2;          // row in chunk 0..15
    const int slot = l & 3;           // 16B slot 0..3
    const int rL0 = (w << 4) + ric;   // local rows
    const int rL1 = rL0 + 64;
    const int sw0 = slot ^ ((rL0 >> 1) & 3);   // pre-swizzled source slot
    const int sw1 = slot ^ ((rL1 >> 1) & 3);
    const ushort* gA0 = X + (size_t)(n0 + rL0) * K + (sw0 << 3);
    const ushort* gA1 = X + (size_t)(n0 + rL1) * K + (sw1 << 3);
    const ushort* gB0 = W + (size_t)(m0 + rL0) * K + (sw0 << 3);
    const ushort* gB1 = W + (size_t)(m0 + rL1) * K + (sw1 << 3);
    ushort* lA0 = As + ((size_t)w << 9);          // wave-uniform chunk bases
    ushort* lA1 = As + ((size_t)(w + 4) << 9);
    ushort* lB0 = Bs + ((size_t)w << 9);
    ushort* lB1 = Bs + ((size_t)(w + 4) << 9);

    // ---- fragment read offsets (constant across K-steps) ----
    const int wr = (w >> 1) & 1, wc = w & 1;
    const int cl = l & 15, kg = l >> 4;
    int aoff[4], boff[4];
    #pragma unroll
    for (int m = 0; m < 4; ++m) {
        const int r = wr * 64 + m * 16 + cl;
        aoff[m] = r * 32 + ((kg ^ ((r >> 1) & 3)) << 3);
    }
    #pragma unroll
    for (int n = 0; n < 4; ++n) {
        const int r = wc * 64 + n * 16 + cl;
        boff[n] = r * 32 + ((kg ^ ((r >> 1) & 3)) << 3);
    }

    f32x4 acc[4][4];
    #pragma unroll
    for (int m = 0; m < 4; ++m)
        #pragma unroll
        for (int n = 0; n < 4; ++n) acc[m][n] = (f32x4){0.f, 0.f, 0.f, 0.f};

    for (int kc = 0; kc < K; kc += 32) {
        GLDS(gA0, lA0); GLDS(gA1, lA1);
        GLDS(gB0, lB0); GLDS(gB1, lB1);
        gA0 += 32; gA1 += 32; gB0 += 32; gB1 += 32;
        __syncthreads();   // drains vmcnt (global_load_lds) + barrier
        bf16x8 av[4], bv[4];
        #pragma unroll
        for (int m = 0; m < 4; ++m) av[m] = *(const bf16x8*)(As + aoff[m]);
        #pragma unroll
        for (int n = 0; n < 4; ++n) bv[n] = *(const bf16x8*)(Bs + boff[n]);
        #pragma unroll
        for (int m = 0; m < 4; ++m)
            #pragma unroll
            for (int n = 0; n < 4; ++n)
                acc[m][n] = __builtin_amdgcn_mfma_f32_16x16x32_bf16(
                    av[m], bv[n], acc[m][n], 0, 0, 0);
        __syncthreads();
    }

    // ---- epilogue: C/D layout col=lane&15, row=(lane>>4)*4+reg ----
    const int colb = m0 + wc * 64 + cl;
    const int rowb = n0 + wr * 64 + (kg << 2);
    float bias[4];
    #pragma unroll
    for (int n = 0; n < 4; ++n) {
        float v = b1[colb + n * 16];
        if (b2 != nullptr) v += b2[colb + n * 16];
        bias[n] = v;
    }
    #pragma unroll
    for (int m = 0; m < 4; ++m) {
        #pragma unroll
        for (int j = 0; j < 4; ++j) {
            const size_t row = (size_t)(rowb + m * 16 + j);
            const size_t base = row * (size_t)M + colb;
            #pragma unroll
            for (int n = 0; n < 4; ++n) {
                const size_t idx = base + n * 16;
                float v = acc[m][n][j] + bias[n];
                if (ACT == 1) v = 1.0f / (1.0f + expf(-v));
                else if (ACT == 2) v = gelu_f(v);
                if (EPI == 1) v *= E[idx];
                else if (EPI == 2) v += E[idx];
                if (ACCUM) v += Cf[idx];
                if (OUTBF) Cb[idx] = f2b(v);
                else       Cf[idx] = v;
            }
        }
    }
}

// ---------------------------------------------------------------------------
// Row LayerNorm over D=256, one wave per row, 4 rows/block.
// ADD: Yf = Yf + ln(X). WF: write fp32 Yf. WB: write bf16 Yb.
// ---------------------------------------------------------------------------
template<int ADD, int WF, int WB>
__global__ __launch_bounds__(256)
void ln_k(const float* __restrict__ X, const float* __restrict__ g,
          const float* __restrict__ bt, float* __restrict__ Yf,
          ushort* __restrict__ Yb)
{
    const int lane = threadIdx.x & 63;
    const int row  = (blockIdx.x << 2) + (threadIdx.x >> 6);
    const size_t base = (size_t)row * Dm + (lane << 2);
    float4 v = *reinterpret_cast<const float4*>(&X[base]);
    float s = v.x + v.y + v.z + v.w;
    #pragma unroll
    for (int o = 1; o < 64; o <<= 1) s += __shfl_xor(s, o);
    const float mu = s * (1.0f / 256.0f);
    const float d0 = v.x - mu, d1 = v.y - mu, d2 = v.z - mu, d3 = v.w - mu;
    float q = d0*d0 + d1*d1 + d2*d2 + d3*d3;
    #pragma unroll
    for (int o = 1; o < 64; o <<= 1) q += __shfl_xor(q, o);
    const float rstd = rsqrtf(q * (1.0f / 256.0f) + 1e-5f);
    const int c = lane << 2;
    const float4 gg = *reinterpret_cast<const float4*>(&g[c]);
    const float4 bb = *reinterpret_cast<const float4*>(&bt[c]);
    float o0 = d0*rstd*gg.x + bb.x, o1 = d1*rstd*gg.y + bb.y;
    float o2 = d2*rstd*gg.z + bb.z, o3 = d3*rstd*gg.w + bb.w;
    if (ADD) {
        const float4 y = *reinterpret_cast<const float4*>(&Yf[base]);
        o0 += y.x; o1 += y.y; o2 += y.z; o3 += y.w;
    }
    if (WF) *reinterpret_cast<float4*>(&Yf[base]) = make_float4(o0, o1, o2, o3);
    if (WB) {
        ushort4 ub; ub.x = f2b(o0); ub.y = f2b(o1); ub.z = f2b(o2); ub.w = f2b(o3);
        *reinterpret_cast<ushort4*>(&Yb[base]) = ub;
    }
}

// ---------------------------------------------------------------------------
// Cross-attention core, bf16 in/out, fp32 math. One (b,h) per block.
// O may alias Q (block-exclusive region; Q consumed into LDS before store).
// ---------------------------------------------------------------------------
__global__ __launch_bounds__(256)
void attn_k(const ushort* __restrict__ Q, const ushort* __restrict__ K,
            const ushort* __restrict__ V, ushort* __restrict__ O)
{
    __shared__ float Qs[32][33], Ks[32][33], Vs[32][33], Ss[32][33];
    const int bh = blockIdx.x;
    const int b = bh >> 3, h = bh & 7;
    const int tid = threadIdx.x;
    const int r  = tid >> 3;
    const int c4 = (tid & 7) << 2;
    const size_t base = ((size_t)b * Lseq + r) * Dm + h * 32 + c4;
    {
        const ushort4 q = *reinterpret_cast<const ushort4*>(&Q[base]);
        Qs[r][c4+0]=b2f(q.x); Qs[r][c4+1]=b2f(q.y); Qs[r][c4+2]=b2f(q.z); Qs[r][c4+3]=b2f(q.w);
        const ushort4 k = *reinterpret_cast<const ushort4*>(&K[base]);
        Ks[r][c4+0]=b2f(k.x); Ks[r][c4+1]=b2f(k.y); Ks[r][c4+2]=b2f(k.z); Ks[r][c4+3]=b2f(k.w);
        const ushort4 v = *reinterpret_cast<const ushort4*>(&V[base]);
        Vs[r][c4+0]=b2f(v.x); Vs[r][c4+1]=b2f(v.y); Vs[r][c4+2]=b2f(v.z); Vs[r][c4+3]=b2f(v.w);
    }
    __syncthreads();
    float sc[4] = {0.f, 0.f, 0.f, 0.f};
    #pragma unroll
    for (int d = 0; d < 32; ++d) {
        const float qv = Qs[r][d];
        #pragma unroll
        for (int j = 0; j < 4; ++j) sc[j] = fmaf(qv, Ks[c4+j][d], sc[j]);
    }
    #pragma unroll
    for (int j = 0; j < 4; ++j) sc[j] *= 0.17677669529663687f;
    float mx = fmaxf(fmaxf(sc[0], sc[1]), fmaxf(sc[2], sc[3]));
    #pragma unroll
    for (int o = 1; o < 8; o <<= 1) mx = fmaxf(mx, __shfl_xor(mx, o));
    float sum = 0.f;
    #pragma unroll
    for (int j = 0; j < 4; ++j) { sc[j] = expf(sc[j] - mx); sum += sc[j]; }
    #pragma unroll
    for (int o = 1; o < 8; o <<= 1) sum += __shfl_xor(sum, o);
    const float inv = 1.0f / sum;
    #pragma unroll
    for (int j = 0; j < 4; ++j) Ss[r][c4+j] = sc[j] * inv;
    __syncthreads();
    float o4[4] = {0.f, 0.f, 0.f, 0.f};
    #pragma unroll
    for (int k = 0; k < 32; ++k) {
        const float wv = Ss[r][k];
        #pragma unroll
        for (int j = 0; j < 4; ++j) o4[j] = fmaf(wv, Vs[k][c4+j], o4[j]);
    }
    ushort4 ob; ob.x=f2b(o4[0]); ob.y=f2b(o4[1]); ob.z=f2b(o4[2]); ob.w=f2b(o4[3]);
    *reinterpret_cast<ushort4*>(&O[base]) = ob;
}

// ---------------------------------------------------------------------------
// SSM scan per batch; x fp32 in, ys bf16 out.
// ---------------------------------------------------------------------------
__global__ __launch_bounds__(256)
void scan_k(const float* __restrict__ Xin, const float* __restrict__ A,
            const float* __restrict__ Bm, const float* __restrict__ Cc,
            ushort* __restrict__ Ys)
{
    __shared__ float xs[32 * 256];
    __shared__ float Cs[256][17];
    __shared__ float As[256];
    __shared__ float xB[32][16];
    __shared__ float hbuf[2][16];
    const int tid = threadIdx.x;
    const size_t base = (size_t)blockIdx.x * (Lseq * Dm);
    #pragma unroll
    for (int i = 0; i < 8; ++i) {
        const int f = (i << 8) + tid;
        *reinterpret_cast<float4*>(&xs[f << 2]) =
            *reinterpret_cast<const float4*>(&Xin[base + ((size_t)f << 2)]);
    }
    {
        const float4* cp = reinterpret_cast<const float4*>(&Cc[tid << 4]);
        #pragma unroll
        for (int i = 0; i < 4; ++i) {
            const float4 cv = cp[i];
            Cs[tid][(i<<2)+0] = cv.x; Cs[tid][(i<<2)+1] = cv.y;
            Cs[tid][(i<<2)+2] = cv.z; Cs[tid][(i<<2)+3] = cv.w;
        }
    }
    As[tid] = A[tid];
    if (tid < 32) hbuf[tid >> 4][tid & 15] = 0.0f;
    __syncthreads();
    #pragma unroll
    for (int rep = 0; rep < 2; ++rep) {
        const int task = tid + (rep << 8);
        const int tt = task >> 4, s = task & 15;
        const float* br = Bm + (s << 8);
        const float* xr = xs + (tt << 8);
        float acc = 0.0f;
        #pragma unroll 8
        for (int d = 0; d < 256; ++d) acc = fmaf(xr[d], br[d], acc);
        xB[tt][s] = acc;
    }
    __syncthreads();
    for (int t = 0; t < 32; ++t) {
        const float* hp = hbuf[t & 1];
        float* hn = hbuf[(t & 1) ^ 1];
        if (tid < 16) {
            float acc = xB[t][tid];
            const float* ar = As + (tid << 4);
            #pragma unroll
            for (int s = 0; s < 16; ++s) acc = fmaf(ar[s], hp[s], acc);
            hn[tid] = acc;
        }
        __syncthreads();
        float acc = 0.0f;
        #pragma unroll
        for (int s = 0; s < 16; ++s) acc = fmaf(hn[s], Cs[tid][s], acc);
        Ys[base + (t << 8) + tid] = f2b(acc);
    }
}

__global__ __launch_bounds__(256)
void meanL_k(const float* __restrict__ X, float* __restrict__ G)
{
    const int idx = blockIdx.x * 256 + threadIdx.x;
    const int b = idx >> 8, d = idx & 255;
    const float* xp = X + (size_t)b * (Lseq * Dm) + d;
    float s = 0.0f;
    #pragma unroll
    for (int t = 0; t < Lseq; ++t) s += xp[t << 8];
    G[idx] = s * (1.0f / 32.0f);
}

__global__ __launch_bounds__(256)
void fillw_k(float* __restrict__ out)
{
    const int i = blockIdx.x * 256 + threadIdx.x;
    const float wm = 1.0f / 32.0f;
    out[i] = wm / (wm + wm + 1e-6f);
}

// fp32 -> bf16 cast, float4-vectorized; n4 = count/4
__global__ __launch_bounds__(256)
void cast_k(const float* __restrict__ src, ushort* __restrict__ dst, int n4)
{
    const int i = blockIdx.x * 256 + threadIdx.x;
    if (i < n4) {
        const float4 v = reinterpret_cast<const float4*>(src)[i];
        ushort4 o; o.x = f2b(v.x); o.y = f2b(v.y); o.z = f2b(v.z); o.w = f2b(v.w);
        reinterpret_cast<ushort4*>(dst)[i] = o;
    }
}

// m_in_w rows [256..511] of each (512,256) block -> 6 contiguous (256,256)
__global__ __launch_bounds__(256)
void cast_inw_k(const float* __restrict__ src, ushort* __restrict__ dst)
{
    const int i = blockIdx.x * 256 + threadIdx.x;   // over 6*16384 float4s
    const int blk = i >> 14, rem = i & 16383;
    const float4 v = reinterpret_cast<const float4*>(
        src + (size_t)blk * 131072 + 65536)[rem];
    ushort4 o; o.x = f2b(v.x); o.y = f2b(v.y); o.z = f2b(v.z); o.w = f2b(v.w);
    reinterpret_cast<ushort4*>(dst)[i] = o;
}

extern "C" void kernel_launch(void* const* d_in, const int* in_sizes, int n_in,
                              void* d_out, int out_size, void* d_ws, size_t ws_size,
                              hipStream_t stream)
{
    const float* ble_f   = (const float*)d_in[0];
    const float* vis_f   = (const float*)d_in[1];
    const float* bp_w    = (const float*)d_in[2];
    const float* bp_b    = (const float*)d_in[3];
    const float* bp_emb  = (const float*)d_in[4];
    const float* bp_g    = (const float*)d_in[5];
    const float* bp_beta = (const float*)d_in[6];
    const float* vp_w    = (const float*)d_in[7];
    const float* vp_b    = (const float*)d_in[8];
    const float* vp_emb  = (const float*)d_in[9];
    const float* vp_g    = (const float*)d_in[10];
    const float* vp_beta = (const float*)d_in[11];
    const float* a_qw    = (const float*)d_in[12];
    const float* a_qb    = (const float*)d_in[13];
    const float* a_kw    = (const float*)d_in[14];
    const float* a_kb    = (const float*)d_in[15];
    const float* a_vw    = (const float*)d_in[16];
    const float* a_vb    = (const float*)d_in[17];
    const float* a_ow    = (const float*)d_in[18];
    const float* a_ob    = (const float*)d_in[19];
    const float* a_g     = (const float*)d_in[20];
    const float* a_beta  = (const float*)d_in[21];
    const float* m_ln1_g = (const float*)d_in[22];
    const float* m_ln1_b = (const float*)d_in[23];
    const float* m_in_w  = (const float*)d_in[24];
    const float* m_in_b  = (const float*)d_in[25];
    const float* m_A     = (const float*)d_in[26];
    const float* m_B     = (const float*)d_in[27];
    const float* m_C     = (const float*)d_in[28];
    const float* m_gw    = (const float*)d_in[29];
    const float* m_gb    = (const float*)d_in[30];
    const float* m_sw    = (const float*)d_in[31];
    const float* m_sb    = (const float*)d_in[32];
    const float* m_ln2_g = (const float*)d_in[33];
    const float* m_ln2_b = (const float*)d_in[34];
    const float* m_f1w   = (const float*)d_in[35];
    const float* m_f1b   = (const float*)d_in[36];
    const float* m_f2w   = (const float*)d_in[37];
    const float* m_f2b   = (const float*)d_in[38];
    const float* fin_g   = (const float*)d_in[39];
    const float* fin_beta= (const float*)d_in[40];
    const float* fin_w   = (const float*)d_in[41];
    const float* fin_b   = (const float*)d_in[42];

    float* out = (float*)d_out;
    float* ws  = (float*)d_ws;
    const size_t NDf = (size_t)NROW * Dm;   // 8.39M elements

    // fp32 buffers
    float* F_res = ws;
    float* F0 = ws + 1 * NDf;
    float* F1 = ws + 2 * NDf;
    float* F2 = ws + 3 * NDf;
    // bf16 slots S0..S4 (each NDf ushorts), then weight arena
    ushort* S0 = (ushort*)(ws + 4 * NDf);
    ushort* S1 = S0 + NDf;
    ushort* S2 = S1 + NDf;
    ushort* S3 = S2 + NDf;
    ushort* S4 = S3 + NDf;
    ushort* Wa = S4 + NDf;
    ushort* W_bp  = Wa;                   // 32768
    ushort* W_vp  = W_bp + 32768;         // 65536
    ushort* W_q   = W_vp + 65536;         // 2*65536
    ushort* W_k   = W_q + 131072;
    ushort* W_v   = W_k + 131072;
    ushort* W_o   = W_v + 131072;
    ushort* W_g   = W_o + 131072;         // 6*65536
    ushort* W_in  = W_g + 393216;
    ushort* W_s   = W_in + 393216;
    ushort* W_f1  = W_s + 393216;         // 6*262144
    ushort* W_f2  = W_f1 + 1572864;
    ushort* W_fin = W_f2 + 1572864;       // 65536
    // input bf16 casts overlay F2 (dead before F2's first use)
    ushort* B_ble = (ushort*)F2;
    ushort* B_vis = B_ble + (size_t)NROW * 128;

    const dim3 blk(256);
    auto cgrid = [](int n4) { return dim3((n4 + 255) / 256); };

    // ---- weight / input casts to bf16 ----
    cast_k<<<cgrid(1048576), blk, 0, stream>>>(ble_f, B_ble, 1048576);
    cast_k<<<cgrid(2097152), blk, 0, stream>>>(vis_f, B_vis, 2097152);
    cast_k<<<cgrid(8192),   blk, 0, stream>>>(bp_w, W_bp, 8192);
    cast_k<<<cgrid(16384),  blk, 0, stream>>>(vp_w, W_vp, 16384);
    cast_k<<<cgrid(32768),  blk, 0, stream>>>(a_qw, W_q, 32768);
    cast_k<<<cgrid(32768),  blk, 0, stream>>>(a_kw, W_k, 32768);
    cast_k<<<cgrid(32768),  blk, 0, stream>>>(a_vw, W_v, 32768);
    cast_k<<<cgrid(32768),  blk, 0, stream>>>(a_ow, W_o, 32768);
    cast_k<<<cgrid(98304),  blk, 0, stream>>>(m_gw, W_g, 98304);
    cast_k<<<cgrid(98304),  blk, 0, stream>>>(m_sw, W_s, 98304);
    cast_k<<<cgrid(393216), blk, 0, stream>>>(m_f1w, W_f1, 393216);
    cast_k<<<cgrid(393216), blk, 0, stream>>>(m_f2w, W_f2, 393216);
    cast_k<<<cgrid(16384),  blk, 0, stream>>>(fin_w, W_fin, 16384);
    cast_inw_k<<<cgrid(98304), blk, 0, stream>>>(m_in_w, W_in);

    auto gg = [](int M, int N) { return dim3(M / 128, N / 128); };

    // ---- input projections + LN (fp32 + bf16 outputs) ----
    mgemm<0,0,false,false><<<gg(256, NROW), blk, 0, stream>>>(B_ble, W_bp, bp_b, bp_emb, nullptr, F0, nullptr, 128, 256);
    ln_k<0,1,1><<<NROW/4, blk, 0, stream>>>(F0, bp_g, bp_beta, F0, S0);
    mgemm<0,0,false,false><<<gg(256, NROW), blk, 0, stream>>>(B_vis, W_vp, vp_b, vp_emb, nullptr, F1, nullptr, 256, 256);
    ln_k<0,1,1><<<NROW/4, blk, 0, stream>>>(F1, vp_g, vp_beta, F1, S1);

    // ---- two cross-attentions ----
    for (int a = 0; a < 2; ++a) {
        const ushort* qin_b = (a == 0) ? S0 : S1;
        const ushort* kin_b = (a == 0) ? S1 : S0;
        const float*  qin_f = (a == 0) ? F0 : F1;
        const size_t wo = (size_t)a * 65536;
        const size_t bo = (size_t)a * 256;
        mgemm<0,0,false,true><<<gg(256, NROW), blk, 0, stream>>>(qin_b, W_q + wo, a_qb + bo, nullptr, nullptr, nullptr, S4, 256, 256);
        mgemm<0,0,false,true><<<gg(256, NROW), blk, 0, stream>>>(kin_b, W_k + wo, a_kb + bo, nullptr, nullptr, nullptr, S2, 256, 256);
        mgemm<0,0,false,true><<<gg(256, NROW), blk, 0, stream>>>(kin_b, W_v + wo, a_vb + bo, nullptr, nullptr, nullptr, S3, 256, 256);
        attn_k<<<Bsz * 8, blk, 0, stream>>>(S4, S2, S3, S4);
        mgemm<0,2,false,false><<<gg(256, NROW), blk, 0, stream>>>(S4, W_o + wo, a_ob + bo, nullptr, qin_f, F2, nullptr, 256, 256);
        if (a == 0) ln_k<0,1,0><<<NROW/4, blk, 0, stream>>>(F2, a_g + bo, a_beta + bo, F_res, nullptr);
        else        ln_k<1,1,0><<<NROW/4, blk, 0, stream>>>(F2, a_g + bo, a_beta + bo, F_res, nullptr);
    }

    // ---- 6 mamba blocks ----
    for (int i = 0; i < 6; ++i) {
        const float* Ai  = m_A + (size_t)i * 256;
        const float* Bi  = m_B + (size_t)i * 16 * 256;
        const float* Ci  = m_C + (size_t)i * 256 * 16;
        ln_k<0,0,1><<<NROW/4, blk, 0, stream>>>(F_res, m_ln1_g + i*256, m_ln1_b + i*256, nullptr, S0);
        // gate = sigmoid(xn @ gw^T + gb) -> F0
        mgemm<1,0,false,false><<<gg(256, NROW), blk, 0, stream>>>(S0, W_g + (size_t)i*65536, m_gb + i*256, nullptr, nullptr, F0, nullptr, 256, 256);
        // x_in = (xn @ inw2^T + inb2) * gate -> F1
        mgemm<0,1,false,false><<<gg(256, NROW), blk, 0, stream>>>(S0, W_in + (size_t)i*65536, m_in_b + (size_t)i*512 + 256, nullptr, F0, F1, nullptr, 256, 256);
        scan_k<<<Bsz, blk, 0, stream>>>(F1, Ai, Bi, Ci, S1);
        // F_res += ys @ sw^T + sb
        mgemm<0,0,true,false><<<gg(256, NROW), blk, 0, stream>>>(S1, W_s + (size_t)i*65536, m_sb + i*256, nullptr, nullptr, F_res, nullptr, 256, 256);
        // FFN
        ln_k<0,0,1><<<NROW/4, blk, 0, stream>>>(F_res, m_ln2_g + i*256, m_ln2_b + i*256, nullptr, S0);
        mgemm<2,0,false,true><<<gg(1024, NROW), blk, 0, stream>>>(S0, W_f1 + (size_t)i*262144, m_f1b + i*1024, nullptr, nullptr, nullptr, S1, 256, 1024);
        mgemm<0,0,true,false><<<gg(256, NROW), blk, 0, stream>>>(S1, W_f2 + (size_t)i*262144, m_f2b + i*256, nullptr, nullptr, F_res, nullptr, 1024, 256);
    }

    // ---- head ----
    meanL_k<<<(Bsz * Dm) / 256, blk, 0, stream>>>(F_res, F0);
    ln_k<0,0,1><<<Bsz/4, blk, 0, stream>>>(F0, fin_g, fin_beta, nullptr, S1);
    mgemm<2,0,false,false><<<gg(256, Bsz), blk, 0, stream>>>(S1, W_fin, fin_b, nullptr, nullptr, out, nullptr, 256, 256);
    fillw_k<<<8, blk, 0, stream>>>(out + (size_t)Bsz * Dm);
}

// Round 3
// 1673.266 us; speedup vs baseline: 3.2259x; 1.0850x over previous
//
#include <hip/hip_runtime.h>
#include <hip/hip_bf16.h>
#include <math.h>

static constexpr int Bsz  = 1024;
static constexpr int Lseq = 32;
static constexpr int Dm   = 256;
static constexpr int NROW = Bsz * Lseq;   // 32768

typedef __attribute__((ext_vector_type(8))) short bf16x8;
typedef __attribute__((ext_vector_type(4))) float f32x4;

__device__ __forceinline__ float gelu_f(float x) {
    return 0.5f * x * (1.0f + erff(x * 0.7071067811865475f));
}
__device__ __forceinline__ float b2f(ushort u) {
    union { float f; uint v; } t; t.v = ((uint)u) << 16; return t.f;
}
__device__ __forceinline__ ushort f2b(float f) {
    union { float f; uint v; } t; t.f = f;
    const uint lsb = (t.v >> 16) & 1u;
    t.v += 0x7fffu + lsb;                 // round-to-nearest-even
    return (ushort)(t.v >> 16);
}

#define GLDS(gp, lp) __builtin_amdgcn_global_load_lds( \
    (const __attribute__((address_space(1))) void*)(gp), \
    (__attribute__((address_space(3))) void*)(lp), 16, 0, 0)

// ---------------------------------------------------------------------------
// bf16 MFMA GEMM (m97 structure): C[n,m] = epi(act(X @ W^T + b1 (+b2)))
// Tile 128x128, BK=32, 256 threads (4 waves, each 64x64 out).
// ACT: 0 none,1 sigmoid,2 gelu.
// EPI: 0 none, 1 mul fp32 E, 2 add fp32 E, 3 mul bf16 Eb.
// ---------------------------------------------------------------------------
template<int ACT, int EPI, bool ACCUM, bool OUTBF>
__global__ __launch_bounds__(256)
void mgemm(const ushort* __restrict__ X, const ushort* __restrict__ W,
           const float* __restrict__ b1, const float* __restrict__ b2,
           const float* __restrict__ E, const ushort* __restrict__ Eb,
           float* __restrict__ Cf, ushort* __restrict__ Cb, int K, int M)
{
    __shared__ ushort As[128 * 32];
    __shared__ ushort Bs[128 * 32];
    const int tid = threadIdx.x;
    const int w = tid >> 6, l = tid & 63;
    const int n0 = blockIdx.y << 7;
    const int m0 = blockIdx.x << 7;

    const int ric  = l >> 2;
    const int slot = l & 3;
    const int rL0 = (w << 4) + ric;
    const int rL1 = rL0 + 64;
    const int sw0 = slot ^ ((rL0 >> 1) & 3);
    const int sw1 = slot ^ ((rL1 >> 1) & 3);
    const ushort* gA0 = X + (size_t)(n0 + rL0) * K + (sw0 << 3);
    const ushort* gA1 = X + (size_t)(n0 + rL1) * K + (sw1 << 3);
    const ushort* gB0 = W + (size_t)(m0 + rL0) * K + (sw0 << 3);
    const ushort* gB1 = W + (size_t)(m0 + rL1) * K + (sw1 << 3);
    ushort* lA0 = As + ((size_t)w << 9);
    ushort* lA1 = As + ((size_t)(w + 4) << 9);
    ushort* lB0 = Bs + ((size_t)w << 9);
    ushort* lB1 = Bs + ((size_t)(w + 4) << 9);

    const int wr = (w >> 1) & 1, wc = w & 1;
    const int cl = l & 15, kg = l >> 4;
    int aoff[4], boff[4];
    #pragma unroll
    for (int m = 0; m < 4; ++m) {
        const int r = wr * 64 + m * 16 + cl;
        aoff[m] = r * 32 + ((kg ^ ((r >> 1) & 3)) << 3);
    }
    #pragma unroll
    for (int n = 0; n < 4; ++n) {
        const int r = wc * 64 + n * 16 + cl;
        boff[n] = r * 32 + ((kg ^ ((r >> 1) & 3)) << 3);
    }

    f32x4 acc[4][4];
    #pragma unroll
    for (int m = 0; m < 4; ++m)
        #pragma unroll
        for (int n = 0; n < 4; ++n) acc[m][n] = (f32x4){0.f, 0.f, 0.f, 0.f};

    for (int kc = 0; kc < K; kc += 32) {
        GLDS(gA0, lA0); GLDS(gA1, lA1);
        GLDS(gB0, lB0); GLDS(gB1, lB1);
        gA0 += 32; gA1 += 32; gB0 += 32; gB1 += 32;
        __syncthreads();
        bf16x8 av[4], bv[4];
        #pragma unroll
        for (int m = 0; m < 4; ++m) av[m] = *(const bf16x8*)(As + aoff[m]);
        #pragma unroll
        for (int n = 0; n < 4; ++n) bv[n] = *(const bf16x8*)(Bs + boff[n]);
        #pragma unroll
        for (int m = 0; m < 4; ++m)
            #pragma unroll
            for (int n = 0; n < 4; ++n)
                acc[m][n] = __builtin_amdgcn_mfma_f32_16x16x32_bf16(
                    av[m], bv[n], acc[m][n], 0, 0, 0);
        __syncthreads();
    }

    const int colb = m0 + wc * 64 + cl;
    const int rowb = n0 + wr * 64 + (kg << 2);
    float bias[4];
    #pragma unroll
    for (int n = 0; n < 4; ++n) {
        float v = b1[colb + n * 16];
        if (b2 != nullptr) v += b2[colb + n * 16];
        bias[n] = v;
    }
    #pragma unroll
    for (int m = 0; m < 4; ++m) {
        #pragma unroll
        for (int j = 0; j < 4; ++j) {
            const size_t row = (size_t)(rowb + m * 16 + j);
            const size_t base = row * (size_t)M + colb;
            #pragma unroll
            for (int n = 0; n < 4; ++n) {
                const size_t idx = base + n * 16;
                float v = acc[m][n][j] + bias[n];
                if (ACT == 1) v = 1.0f / (1.0f + expf(-v));
                else if (ACT == 2) v = gelu_f(v);
                if (EPI == 1) v *= E[idx];
                else if (EPI == 2) v += E[idx];
                else if (EPI == 3) v *= b2f(Eb[idx]);
                if (ACCUM) v += Cf[idx];
                if (OUTBF) Cb[idx] = f2b(v);
                else       Cf[idx] = v;
            }
        }
    }
}

// ---------------------------------------------------------------------------
// Row LayerNorm over D=256, one wave per row, 4 rows/block.
// ---------------------------------------------------------------------------
template<int ADD, int WF, int WB>
__global__ __launch_bounds__(256)
void ln_k(const float* __restrict__ X, const float* __restrict__ g,
          const float* __restrict__ bt, float* __restrict__ Yf,
          ushort* __restrict__ Yb)
{
    const int lane = threadIdx.x & 63;
    const int row  = (blockIdx.x << 2) + (threadIdx.x >> 6);
    const size_t base = (size_t)row * Dm + (lane << 2);
    float4 v = *reinterpret_cast<const float4*>(&X[base]);
    float s = v.x + v.y + v.z + v.w;
    #pragma unroll
    for (int o = 1; o < 64; o <<= 1) s += __shfl_xor(s, o);
    const float mu = s * (1.0f / 256.0f);
    const float d0 = v.x - mu, d1 = v.y - mu, d2 = v.z - mu, d3 = v.w - mu;
    float q = d0*d0 + d1*d1 + d2*d2 + d3*d3;
    #pragma unroll
    for (int o = 1; o < 64; o <<= 1) q += __shfl_xor(q, o);
    const float rstd = rsqrtf(q * (1.0f / 256.0f) + 1e-5f);
    const int c = lane << 2;
    const float4 gg = *reinterpret_cast<const float4*>(&g[c]);
    const float4 bb = *reinterpret_cast<const float4*>(&bt[c]);
    float o0 = d0*rstd*gg.x + bb.x, o1 = d1*rstd*gg.y + bb.y;
    float o2 = d2*rstd*gg.z + bb.z, o3 = d3*rstd*gg.w + bb.w;
    if (ADD) {
        const float4 y = *reinterpret_cast<const float4*>(&Yf[base]);
        o0 += y.x; o1 += y.y; o2 += y.z; o3 += y.w;
    }
    if (WF) *reinterpret_cast<float4*>(&Yf[base]) = make_float4(o0, o1, o2, o3);
    if (WB) {
        ushort4 ub; ub.x = f2b(o0); ub.y = f2b(o1); ub.z = f2b(o2); ub.w = f2b(o3);
        *reinterpret_cast<ushort4*>(&Yb[base]) = ub;
    }
}

// ---------------------------------------------------------------------------
// Cross-attention core, bf16 in/out, fp32 math. One (b,h) per block.
// ---------------------------------------------------------------------------
__global__ __launch_bounds__(256)
void attn_k(const ushort* __restrict__ Q, const ushort* __restrict__ K,
            const ushort* __restrict__ V, ushort* __restrict__ O)
{
    __shared__ float Qs[32][33], Ks[32][33], Vs[32][33], Ss[32][33];
    const int bh = blockIdx.x;
    const int b = bh >> 3, h = bh & 7;
    const int tid = threadIdx.x;
    const int r  = tid >> 3;
    const int c4 = (tid & 7) << 2;
    const size_t base = ((size_t)b * Lseq + r) * Dm + h * 32 + c4;
    {
        const ushort4 q = *reinterpret_cast<const ushort4*>(&Q[base]);
        Qs[r][c4+0]=b2f(q.x); Qs[r][c4+1]=b2f(q.y); Qs[r][c4+2]=b2f(q.z); Qs[r][c4+3]=b2f(q.w);
        const ushort4 k = *reinterpret_cast<const ushort4*>(&K[base]);
        Ks[r][c4+0]=b2f(k.x); Ks[r][c4+1]=b2f(k.y); Ks[r][c4+2]=b2f(k.z); Ks[r][c4+3]=b2f(k.w);
        const ushort4 v = *reinterpret_cast<const ushort4*>(&V[base]);
        Vs[r][c4+0]=b2f(v.x); Vs[r][c4+1]=b2f(v.y); Vs[r][c4+2]=b2f(v.z); Vs[r][c4+3]=b2f(v.w);
    }
    __syncthreads();
    float sc[4] = {0.f, 0.f, 0.f, 0.f};
    #pragma unroll
    for (int d = 0; d < 32; ++d) {
        const float qv = Qs[r][d];
        #pragma unroll
        for (int j = 0; j < 4; ++j) sc[j] = fmaf(qv, Ks[c4+j][d], sc[j]);
    }
    #pragma unroll
    for (int j = 0; j < 4; ++j) sc[j] *= 0.17677669529663687f;
    float mx = fmaxf(fmaxf(sc[0], sc[1]), fmaxf(sc[2], sc[3]));
    #pragma unroll
    for (int o = 1; o < 8; o <<= 1) mx = fmaxf(mx, __shfl_xor(mx, o));
    float sum = 0.f;
    #pragma unroll
    for (int j = 0; j < 4; ++j) { sc[j] = expf(sc[j] - mx); sum += sc[j]; }
    #pragma unroll
    for (int o = 1; o < 8; o <<= 1) sum += __shfl_xor(sum, o);
    const float inv = 1.0f / sum;
    #pragma unroll
    for (int j = 0; j < 4; ++j) Ss[r][c4+j] = sc[j] * inv;
    __syncthreads();
    float o4[4] = {0.f, 0.f, 0.f, 0.f};
    #pragma unroll
    for (int k = 0; k < 32; ++k) {
        const float wv = Ss[r][k];
        #pragma unroll
        for (int j = 0; j < 4; ++j) o4[j] = fmaf(wv, Vs[k][c4+j], o4[j]);
    }
    ushort4 ob; ob.x=f2b(o4[0]); ob.y=f2b(o4[1]); ob.z=f2b(o4[2]); ob.w=f2b(o4[3]);
    *reinterpret_cast<ushort4*>(&O[base]) = ob;
}

// ---------------------------------------------------------------------------
// W_scpad[i][m][s] = sum_d sw[i][m][d] * C[i][d][s], bf16, s in [16,32) = 0.
// Grid 6*16 blocks x 256 threads; one output per thread.
// ---------------------------------------------------------------------------
__global__ __launch_bounds__(256)
void wsc_k(const float* __restrict__ sw, const float* __restrict__ Cc,
           ushort* __restrict__ Wp)
{
    const int i = blockIdx.x >> 4;
    const int m = ((blockIdx.x & 15) << 4) + (threadIdx.x >> 4);
    const int s = threadIdx.x & 15;
    const float* swr = sw + ((size_t)i << 16) + (m << 8);
    const float* cc  = Cc + ((size_t)i << 12) + s;
    float acc = 0.0f;
    #pragma unroll 8
    for (int d = 0; d < 256; ++d) acc = fmaf(swr[d], cc[d << 4], acc);
    ushort* o = Wp + ((size_t)i << 13) + (m << 5);
    o[s] = f2b(acc);
    o[s + 16] = 0;
}

// ---------------------------------------------------------------------------
// scanB: per batch, xB = x_in @ Bm^T (from LDS-staged x_in), then the 32-step
// 16-dim recurrence in ONE wave via __shfl (no barriers), h -> Hp (N,32) bf16
// with cols 16..31 zeroed.
// ---------------------------------------------------------------------------
__global__ __launch_bounds__(256)
void scanB_k(const ushort* __restrict__ Xin, const float* __restrict__ A,
             const float* __restrict__ Bm, ushort* __restrict__ Hp)
{
    __shared__ float xs[32][257];
    __shared__ float xB[32][17];
    __shared__ float hall[32][20];
    const int tid = threadIdx.x;
    const size_t base = (size_t)blockIdx.x << 13;    // *32*256
    #pragma unroll
    for (int i = 0; i < 4; ++i) {
        const int u = (i << 8) + tid;                // ushort8 index 0..1023
        const int row = u >> 5;
        const int c8  = (u & 31) << 3;
        const ushort4 p0 = *reinterpret_cast<const ushort4*>(&Xin[base + row * 256 + c8]);
        const ushort4 p1 = *reinterpret_cast<const ushort4*>(&Xin[base + row * 256 + c8 + 4]);
        xs[row][c8+0] = b2f(p0.x); xs[row][c8+1] = b2f(p0.y);
        xs[row][c8+2] = b2f(p0.z); xs[row][c8+3] = b2f(p0.w);
        xs[row][c8+4] = b2f(p1.x); xs[row][c8+5] = b2f(p1.y);
        xs[row][c8+6] = b2f(p1.z); xs[row][c8+7] = b2f(p1.w);
    }
    __syncthreads();
    #pragma unroll
    for (int rep = 0; rep < 2; ++rep) {
        const int task = (rep << 8) + tid;           // 0..511
        const int tt = task >> 4, s = task & 15;
        const float* br = Bm + (s << 8);
        float acc = 0.0f;
        #pragma unroll 8
        for (int d = 0; d < 256; ++d) acc = fmaf(xs[tt][d], br[d], acc);
        xB[tt][s] = acc;
    }
    __syncthreads();
    if (tid < 64) {
        const int s = tid & 15;
        float a[16];
        #pragma unroll
        for (int k = 0; k < 16; ++k) a[k] = A[s * 16 + k];
        float h = 0.0f;
        for (int t = 0; t < 32; ++t) {
            float acc = xB[t][s];
            #pragma unroll
            for (int k = 0; k < 16; ++k) acc = fmaf(a[k], __shfl(h, k), acc);
            h = acc;
            if (tid < 16) hall[t][s] = h;
        }
    }
    __syncthreads();
    {
        const int row = tid >> 3;
        const int c4  = (tid & 7) << 2;
        ushort4 o;
        if (c4 < 16) {
            o.x = f2b(hall[row][c4+0]); o.y = f2b(hall[row][c4+1]);
            o.z = f2b(hall[row][c4+2]); o.w = f2b(hall[row][c4+3]);
        } else { o.x = 0; o.y = 0; o.z = 0; o.w = 0; }
        *reinterpret_cast<ushort4*>(&Hp[((size_t)blockIdx.x << 10) + row * 32 + c4]) = o;
    }
}

__global__ __launch_bounds__(256)
void meanL_k(const float* __restrict__ X, float* __restrict__ G)
{
    const int idx = blockIdx.x * 256 + threadIdx.x;
    const int b = idx >> 8, d = idx & 255;
    const float* xp = X + (size_t)b * (Lseq * Dm) + d;
    float s = 0.0f;
    #pragma unroll
    for (int t = 0; t < Lseq; ++t) s += xp[t << 8];
    G[idx] = s * (1.0f / 32.0f);
}

__global__ __launch_bounds__(256)
void fillw_k(float* __restrict__ out)
{
    const int i = blockIdx.x * 256 + threadIdx.x;
    const float wm = 1.0f / 32.0f;
    out[i] = wm / (wm + wm + 1e-6f);
}

__global__ __launch_bounds__(256)
void cast_k(const float* __restrict__ src, ushort* __restrict__ dst, int n4)
{
    const int i = blockIdx.x * 256 + threadIdx.x;
    if (i < n4) {
        const float4 v = reinterpret_cast<const float4*>(src)[i];
        ushort4 o; o.x = f2b(v.x); o.y = f2b(v.y); o.z = f2b(v.z); o.w = f2b(v.w);
        reinterpret_cast<ushort4*>(dst)[i] = o;
    }
}

__global__ __launch_bounds__(256)
void cast_inw_k(const float* __restrict__ src, ushort* __restrict__ dst)
{
    const int i = blockIdx.x * 256 + threadIdx.x;
    const int blk = i >> 14, rem = i & 16383;
    const float4 v = reinterpret_cast<const float4*>(
        src + (size_t)blk * 131072 + 65536)[rem];
    ushort4 o; o.x = f2b(v.x); o.y = f2b(v.y); o.z = f2b(v.z); o.w = f2b(v.w);
    reinterpret_cast<ushort4*>(dst)[i] = o;
}

extern "C" void kernel_launch(void* const* d_in, const int* in_sizes, int n_in,
                              void* d_out, int out_size, void* d_ws, size_t ws_size,
                              hipStream_t stream)
{
    const float* ble_f   = (const float*)d_in[0];
    const float* vis_f   = (const float*)d_in[1];
    const float* bp_w    = (const float*)d_in[2];
    const float* bp_b    = (const float*)d_in[3];
    const float* bp_emb  = (const float*)d_in[4];
    const float* bp_g    = (const float*)d_in[5];
    const float* bp_beta = (const float*)d_in[6];
    const float* vp_w    = (const float*)d_in[7];
    const float* vp_b    = (const float*)d_in[8];
    const float* vp_emb  = (const float*)d_in[9];
    const float* vp_g    = (const float*)d_in[10];
    const float* vp_beta = (const float*)d_in[11];
    const float* a_qw    = (const float*)d_in[12];
    const float* a_qb    = (const float*)d_in[13];
    const float* a_kw    = (const float*)d_in[14];
    const float* a_kb    = (const float*)d_in[15];
    const float* a_vw    = (const float*)d_in[16];
    const float* a_vb    = (const float*)d_in[17];
    const float* a_ow    = (const float*)d_in[18];
    const float* a_ob    = (const float*)d_in[19];
    const float* a_g     = (const float*)d_in[20];
    const float* a_beta  = (const float*)d_in[21];
    const float* m_ln1_g = (const float*)d_in[22];
    const float* m_ln1_b = (const float*)d_in[23];
    const float* m_in_w  = (const float*)d_in[24];
    const float* m_in_b  = (const float*)d_in[25];
    const float* m_A     = (const float*)d_in[26];
    const float* m_B     = (const float*)d_in[27];
    const float* m_C     = (const float*)d_in[28];
    const float* m_gw    = (const float*)d_in[29];
    const float* m_gb    = (const float*)d_in[30];
    const float* m_sw    = (const float*)d_in[31];
    const float* m_sb    = (const float*)d_in[32];
    const float* m_ln2_g = (const float*)d_in[33];
    const float* m_ln2_b = (const float*)d_in[34];
    const float* m_f1w   = (const float*)d_in[35];
    const float* m_f1b   = (const float*)d_in[36];
    const float* m_f2w   = (const float*)d_in[37];
    const float* m_f2b   = (const float*)d_in[38];
    const float* fin_g   = (const float*)d_in[39];
    const float* fin_beta= (const float*)d_in[40];
    const float* fin_w   = (const float*)d_in[41];
    const float* fin_b   = (const float*)d_in[42];

    float* out = (float*)d_out;
    float* ws  = (float*)d_ws;
    const size_t NDf = (size_t)NROW * Dm;   // 8.39M elements

    float* F_res = ws;
    float* F0 = ws + 1 * NDf;
    float* F1 = ws + 2 * NDf;
    float* F2 = ws + 3 * NDf;
    ushort* S0 = (ushort*)(ws + 4 * NDf);
    ushort* S1 = S0 + NDf;
    ushort* S2 = S1 + NDf;
    ushort* S3 = S2 + NDf;
    ushort* S4 = S3 + NDf;
    ushort* Wa = S4 + NDf;
    ushort* W_bp  = Wa;                   // 32768
    ushort* W_vp  = W_bp + 32768;         // 65536
    ushort* W_q   = W_vp + 65536;         // 2*65536
    ushort* W_k   = W_q + 131072;
    ushort* W_v   = W_k + 131072;
    ushort* W_o   = W_v + 131072;
    ushort* W_g   = W_o + 131072;         // 6*65536
    ushort* W_in  = W_g + 393216;
    ushort* W_f1  = W_in + 393216;        // 6*262144
    ushort* W_f2  = W_f1 + 1572864;
    ushort* W_fin = W_f2 + 1572864;       // 65536
    ushort* W_sc  = W_fin + 65536;        // 6*8192 (padded K=32)
    ushort* Hpad  = W_sc + 49152;         // 32768*32
    ushort* B_ble = (ushort*)F2;          // overlay (dead before F2 first use)
    ushort* B_vis = B_ble + (size_t)NROW * 128;

    const dim3 blk(256);
    auto cgrid = [](int n4) { return dim3((n4 + 255) / 256); };

    // ---- weight / input casts + sw@C fold ----
    cast_k<<<cgrid(1048576), blk, 0, stream>>>(ble_f, B_ble, 1048576);
    cast_k<<<cgrid(2097152), blk, 0, stream>>>(vis_f, B_vis, 2097152);
    cast_k<<<cgrid(8192),   blk, 0, stream>>>(bp_w, W_bp, 8192);
    cast_k<<<cgrid(16384),  blk, 0, stream>>>(vp_w, W_vp, 16384);
    cast_k<<<cgrid(32768),  blk, 0, stream>>>(a_qw, W_q, 32768);
    cast_k<<<cgrid(32768),  blk, 0, stream>>>(a_kw, W_k, 32768);
    cast_k<<<cgrid(32768),  blk, 0, stream>>>(a_vw, W_v, 32768);
    cast_k<<<cgrid(32768),  blk, 0, stream>>>(a_ow, W_o, 32768);
    cast_k<<<cgrid(98304),  blk, 0, stream>>>(m_gw, W_g, 98304);
    cast_k<<<cgrid(393216), blk, 0, stream>>>(m_f1w, W_f1, 393216);
    cast_k<<<cgrid(393216), blk, 0, stream>>>(m_f2w, W_f2, 393216);
    cast_k<<<cgrid(16384),  blk, 0, stream>>>(fin_w, W_fin, 16384);
    cast_inw_k<<<cgrid(98304), blk, 0, stream>>>(m_in_w, W_in);
    wsc_k<<<96, blk, 0, stream>>>(m_sw, m_C, W_sc);

    auto gg = [](int M, int N) { return dim3(M / 128, N / 128); };

    // ---- input projections + LN ----
    mgemm<0,0,false,false><<<gg(256, NROW), blk, 0, stream>>>(B_ble, W_bp, bp_b, bp_emb, nullptr, nullptr, F0, nullptr, 128, 256);
    ln_k<0,1,1><<<NROW/4, blk, 0, stream>>>(F0, bp_g, bp_beta, F0, S0);
    mgemm<0,0,false,false><<<gg(256, NROW), blk, 0, stream>>>(B_vis, W_vp, vp_b, vp_emb, nullptr, nullptr, F1, nullptr, 256, 256);
    ln_k<0,1,1><<<NROW/4, blk, 0, stream>>>(F1, vp_g, vp_beta, F1, S1);

    // ---- two cross-attentions ----
    for (int a = 0; a < 2; ++a) {
        const ushort* qin_b = (a == 0) ? S0 : S1;
        const ushort* kin_b = (a == 0) ? S1 : S0;
        const float*  qin_f = (a == 0) ? F0 : F1;
        const size_t wo = (size_t)a * 65536;
        const size_t bo = (size_t)a * 256;
        mgemm<0,0,false,true><<<gg(256, NROW), blk, 0, stream>>>(qin_b, W_q + wo, a_qb + bo, nullptr, nullptr, nullptr, nullptr, S4, 256, 256);
        mgemm<0,0,false,true><<<gg(256, NROW), blk, 0, stream>>>(kin_b, W_k + wo, a_kb + bo, nullptr, nullptr, nullptr, nullptr, S2, 256, 256);
        mgemm<0,0,false,true><<<gg(256, NROW), blk, 0, stream>>>(kin_b, W_v + wo, a_vb + bo, nullptr, nullptr, nullptr, nullptr, S3, 256, 256);
        attn_k<<<Bsz * 8, blk, 0, stream>>>(S4, S2, S3, S4);
        mgemm<0,2,false,false><<<gg(256, NROW), blk, 0, stream>>>(S4, W_o + wo, a_ob + bo, nullptr, qin_f, nullptr, F2, nullptr, 256, 256);
        if (a == 0) ln_k<0,1,0><<<NROW/4, blk, 0, stream>>>(F2, a_g + bo, a_beta + bo, F_res, nullptr);
        else        ln_k<1,1,0><<<NROW/4, blk, 0, stream>>>(F2, a_g + bo, a_beta + bo, F_res, nullptr);
    }

    // ---- 6 mamba blocks ----
    for (int i = 0; i < 6; ++i) {
        ln_k<0,0,1><<<NROW/4, blk, 0, stream>>>(F_res, m_ln1_g + i*256, m_ln1_b + i*256, nullptr, S0);
        // gate = sigmoid(xn @ gw^T + gb) -> S3 (bf16)
        mgemm<1,0,false,true><<<gg(256, NROW), blk, 0, stream>>>(S0, W_g + (size_t)i*65536, m_gb + i*256, nullptr, nullptr, nullptr, nullptr, S3, 256, 256);
        // x_in = (xn @ inw2^T + inb2) * gate -> S2 (bf16)
        mgemm<0,3,false,true><<<gg(256, NROW), blk, 0, stream>>>(S0, W_in + (size_t)i*65536, m_in_b + (size_t)i*512 + 256, nullptr, nullptr, S3, nullptr, S2, 256, 256);
        // h states (folded C into sout weights)
        scanB_k<<<Bsz, blk, 0, stream>>>(S2, m_A + (size_t)i*256, m_B + (size_t)i*4096, Hpad);
        // F_res += h @ (sw@C)^T + sb   (K=32)
        mgemm<0,0,true,false><<<gg(256, NROW), blk, 0, stream>>>(Hpad, W_sc + (size_t)i*8192, m_sb + i*256, nullptr, nullptr, nullptr, F_res, nullptr, 32, 256);
        // FFN
        ln_k<0,0,1><<<NROW/4, blk, 0, stream>>>(F_res, m_ln2_g + i*256, m_ln2_b + i*256, nullptr, S0);
        mgemm<2,0,false,true><<<gg(1024, NROW), blk, 0, stream>>>(S0, W_f1 + (size_t)i*262144, m_f1b + i*1024, nullptr, nullptr, nullptr, nullptr, S1, 256, 1024);
        mgemm<0,0,true,false><<<gg(256, NROW), blk, 0, stream>>>(S1, W_f2 + (size_t)i*262144, m_f2b + i*256, nullptr, nullptr, nullptr, F_res, nullptr, 1024, 256);
    }

    // ---- head ----
    meanL_k<<<(Bsz * Dm) / 256, blk, 0, stream>>>(F_res, F0);
    ln_k<0,0,1><<<Bsz/4, blk, 0, stream>>>(F0, fin_g, fin_beta, nullptr, S1);
    mgemm<2,0,false,false><<<gg(256, Bsz), blk, 0, stream>>>(S1, W_fin, fin_b, nullptr, nullptr, nullptr, out, nullptr, 256, 256);
    fillw_k<<<8, blk, 0, stream>>>(out + (size_t)Bsz * Dm);
}

// Round 4
// 1431.327 us; speedup vs baseline: 3.7711x; 1.1690x over previous
//
#include <hip/hip_runtime.h>
#include <hip/hip_bf16.h>
#include <math.h>

static constexpr int Bsz  = 1024;
static constexpr int Lseq = 32;
static constexpr int Dm   = 256;
static constexpr int NROW = Bsz * Lseq;   // 32768

typedef __attribute__((ext_vector_type(8))) short bf16x8;
typedef __attribute__((ext_vector_type(4))) float f32x4;

__device__ __forceinline__ float gelu_f(float x) {
    return 0.5f * x * (1.0f + erff(x * 0.7071067811865475f));
}
__device__ __forceinline__ float b2f(ushort u) {
    union { float f; uint v; } t; t.v = ((uint)u) << 16; return t.f;
}
__device__ __forceinline__ ushort f2b(float f) {
    union { float f; uint v; } t; t.f = f;
    const uint lsb = (t.v >> 16) & 1u;
    t.v += 0x7fffu + lsb;                 // round-to-nearest-even
    return (ushort)(t.v >> 16);
}

#define GLDS(gp, lp) __builtin_amdgcn_global_load_lds( \
    (const __attribute__((address_space(1))) void*)(gp), \
    (__attribute__((address_space(3))) void*)(lp), 16, 0, 0)

// ---------------------------------------------------------------------------
// bf16 MFMA GEMM (m97 structure): C[n,m] = epi(act(X @ W^T + b1 (+b2)))
// Tile 128x128, BK=32, 256 threads (4 waves, each 64x64 out).
// ACT: 0 none,1 sigmoid,2 gelu. EPI: 0 none,1 mul f32 E,2 add f32 E,3 mul bf16 Eb.
// OMAP: 0 normal row*M+col; 1 scan-H remap idx = row*1024 + (col>>4)*32 + (col&15)
//       (writes H(1024x512) GEMM output directly into Hpad(32768x32) layout).
// b1 may be nullptr (zero bias).
// ---------------------------------------------------------------------------
template<int ACT, int EPI, bool ACCUM, bool OUTBF, int OMAP>
__global__ __launch_bounds__(256)
void mgemm(const ushort* __restrict__ X, const ushort* __restrict__ W,
           const float* __restrict__ b1, const float* __restrict__ b2,
           const float* __restrict__ E, const ushort* __restrict__ Eb,
           float* __restrict__ Cf, ushort* __restrict__ Cb, int K, int M)
{
    __shared__ ushort As[128 * 32];
    __shared__ ushort Bs[128 * 32];
    const int tid = threadIdx.x;
    const int w = tid >> 6, l = tid & 63;
    const int n0 = blockIdx.y << 7;
    const int m0 = blockIdx.x << 7;

    const int ric  = l >> 2;
    const int slot = l & 3;
    const int rL0 = (w << 4) + ric;
    const int rL1 = rL0 + 64;
    const int sw0 = slot ^ ((rL0 >> 1) & 3);
    const int sw1 = slot ^ ((rL1 >> 1) & 3);
    const ushort* gA0 = X + (size_t)(n0 + rL0) * K + (sw0 << 3);
    const ushort* gA1 = X + (size_t)(n0 + rL1) * K + (sw1 << 3);
    const ushort* gB0 = W + (size_t)(m0 + rL0) * K + (sw0 << 3);
    const ushort* gB1 = W + (size_t)(m0 + rL1) * K + (sw1 << 3);
    ushort* lA0 = As + ((size_t)w << 9);
    ushort* lA1 = As + ((size_t)(w + 4) << 9);
    ushort* lB0 = Bs + ((size_t)w << 9);
    ushort* lB1 = Bs + ((size_t)(w + 4) << 9);

    const int wr = (w >> 1) & 1, wc = w & 1;
    const int cl = l & 15, kg = l >> 4;
    int aoff[4], boff[4];
    #pragma unroll
    for (int m = 0; m < 4; ++m) {
        const int r = wr * 64 + m * 16 + cl;
        aoff[m] = r * 32 + ((kg ^ ((r >> 1) & 3)) << 3);
    }
    #pragma unroll
    for (int n = 0; n < 4; ++n) {
        const int r = wc * 64 + n * 16 + cl;
        boff[n] = r * 32 + ((kg ^ ((r >> 1) & 3)) << 3);
    }

    f32x4 acc[4][4];
    #pragma unroll
    for (int m = 0; m < 4; ++m)
        #pragma unroll
        for (int n = 0; n < 4; ++n) acc[m][n] = (f32x4){0.f, 0.f, 0.f, 0.f};

    for (int kc = 0; kc < K; kc += 32) {
        GLDS(gA0, lA0); GLDS(gA1, lA1);
        GLDS(gB0, lB0); GLDS(gB1, lB1);
        gA0 += 32; gA1 += 32; gB0 += 32; gB1 += 32;
        __syncthreads();
        bf16x8 av[4], bv[4];
        #pragma unroll
        for (int m = 0; m < 4; ++m) av[m] = *(const bf16x8*)(As + aoff[m]);
        #pragma unroll
        for (int n = 0; n < 4; ++n) bv[n] = *(const bf16x8*)(Bs + boff[n]);
        #pragma unroll
        for (int m = 0; m < 4; ++m)
            #pragma unroll
            for (int n = 0; n < 4; ++n)
                acc[m][n] = __builtin_amdgcn_mfma_f32_16x16x32_bf16(
                    av[m], bv[n], acc[m][n], 0, 0, 0);
        __syncthreads();
    }

    const int colb = m0 + wc * 64 + cl;
    const int rowb = n0 + wr * 64 + (kg << 2);
    float bias[4];
    #pragma unroll
    for (int n = 0; n < 4; ++n) {
        float v = (b1 != nullptr) ? b1[colb + n * 16] : 0.0f;
        if (b2 != nullptr) v += b2[colb + n * 16];
        bias[n] = v;
    }
    #pragma unroll
    for (int m = 0; m < 4; ++m) {
        #pragma unroll
        for (int j = 0; j < 4; ++j) {
            const size_t row = (size_t)(rowb + m * 16 + j);
            #pragma unroll
            for (int n = 0; n < 4; ++n) {
                const int col = colb + n * 16;
                size_t idx;
                if (OMAP == 1) idx = row * 1024 + ((size_t)(col >> 4) << 5) + (col & 15);
                else           idx = row * (size_t)M + col;
                float v = acc[m][n][j] + bias[n];
                if (ACT == 1) v = 1.0f / (1.0f + expf(-v));
                else if (ACT == 2) v = gelu_f(v);
                if (EPI == 1) v *= E[idx];
                else if (EPI == 2) v += E[idx];
                else if (EPI == 3) v *= b2f(Eb[idx]);
                if (ACCUM) v += Cf[idx];
                if (OUTBF) Cb[idx] = f2b(v);
                else       Cf[idx] = v;
            }
        }
    }
}

// ---------------------------------------------------------------------------
// XB GEMM: XB[n, s] = sum_d X[n,d] * Bw[s,d]   (N x 16, K=256, bf16 out)
// Grid NROW/128 blocks, 256 thr (4 waves, each 32 rows x 16 cols).
// Bw (16x256) staged whole in XOR-swizzled LDS; A staged per-K-step via GLDS.
// ---------------------------------------------------------------------------
__global__ __launch_bounds__(256)
void xb_gemm(const ushort* __restrict__ X, const ushort* __restrict__ Bw,
             ushort* __restrict__ XB)
{
    __shared__ ushort As[128 * 32];
    __shared__ ushort Bsf[16 * 256];
    const int tid = threadIdx.x;
    const int w = tid >> 6, l = tid & 63;
    const int n0 = blockIdx.x << 7;
    // stage Bw swizzled (ushort idx ^= (row&7)<<3)
    #pragma unroll
    for (int rep = 0; rep < 2; ++rep) {
        const int u = (rep << 8) + tid;       // 0..511
        const int r = u >> 5;
        const int c8 = (u & 31) << 3;
        const int di = (r * 256 + c8) ^ ((r & 7) << 3);
        *(bf16x8*)(Bsf + di) = *(const bf16x8*)(Bw + r * 256 + c8);
    }
    const int ric = l >> 2, slot = l & 3;
    const int rL0 = (w << 4) + ric, rL1 = rL0 + 64;
    const int sw0 = slot ^ ((rL0 >> 1) & 3), sw1 = slot ^ ((rL1 >> 1) & 3);
    const ushort* gA0 = X + (size_t)(n0 + rL0) * 256 + (sw0 << 3);
    const ushort* gA1 = X + (size_t)(n0 + rL1) * 256 + (sw1 << 3);
    ushort* lA0 = As + (w << 9);
    ushort* lA1 = As + ((w + 4) << 9);
    const int cl = l & 15, kg = l >> 4;
    int aoff[2];
    #pragma unroll
    for (int m = 0; m < 2; ++m) {
        const int r = w * 32 + m * 16 + cl;
        aoff[m] = r * 32 + ((kg ^ ((r >> 1) & 3)) << 3);
    }
    f32x4 acc[2] = {(f32x4){0.f,0.f,0.f,0.f}, (f32x4){0.f,0.f,0.f,0.f}};
    for (int kc = 0; kc < 256; kc += 32) {
        GLDS(gA0, lA0); GLDS(gA1, lA1);
        gA0 += 32; gA1 += 32;
        __syncthreads();
        const bf16x8 av0 = *(const bf16x8*)(As + aoff[0]);
        const bf16x8 av1 = *(const bf16x8*)(As + aoff[1]);
        const int bidx = (cl * 256 + kc + (kg << 3)) ^ ((cl & 7) << 3);
        const bf16x8 bv = *(const bf16x8*)(Bsf + bidx);
        acc[0] = __builtin_amdgcn_mfma_f32_16x16x32_bf16(av0, bv, acc[0], 0, 0, 0);
        acc[1] = __builtin_amdgcn_mfma_f32_16x16x32_bf16(av1, bv, acc[1], 0, 0, 0);
        __syncthreads();
    }
    #pragma unroll
    for (int m = 0; m < 2; ++m)
        #pragma unroll
        for (int j = 0; j < 4; ++j) {
            const int row = n0 + w * 32 + m * 16 + (kg << 2) + j;
            XB[(size_t)row * 16 + cl] = f2b(acc[m][j]);
        }
}

// ---------------------------------------------------------------------------
// powT: per layer, T[t*16+s'][tau*16+s] = (A^(t-tau))[s'][s] for t>=tau else 0.
// Grid 6 blocks x 256 threads. T bf16 512x512 per layer.
// ---------------------------------------------------------------------------
__global__ __launch_bounds__(256)
void powT_k(const float* __restrict__ A_all, ushort* __restrict__ T_all)
{
    __shared__ float P[2][16][16];
    __shared__ float Asm[16][16];
    const int layer = blockIdx.x;
    const float* A = A_all + layer * 256;
    ushort* T = T_all + (size_t)layer * 262144;
    const int tid = threadIdx.x;
    const int i = tid >> 4, j = tid & 15;
    Asm[i][j] = A[tid];
    // zero whole T layer
    const bf16x8 z = {0,0,0,0,0,0,0,0};
    for (int u = tid; u < 32768; u += 256)
        *(bf16x8*)(T + (size_t)u * 8) = z;
    P[0][i][j] = (i == j) ? 1.0f : 0.0f;
    __syncthreads();
    for (int k = 0; k < 32; ++k) {
        const float pv = P[k & 1][i][j];
        const ushort pb = f2b(pv);
        for (int tau = 0; tau + k < 32; ++tau)
            T[(size_t)((tau + k) * 16 + i) * 512 + tau * 16 + j] = pb;
        float acc = 0.0f;
        #pragma unroll
        for (int l2 = 0; l2 < 16; ++l2) acc = fmaf(P[k & 1][i][l2], Asm[l2][j], acc);
        P[(k & 1) ^ 1][i][j] = acc;
        __syncthreads();
    }
}

// zero Hpad (32768 x 32 bf16)
__global__ __launch_bounds__(256)
void zeroH_k(ushort* __restrict__ Hp)
{
    const int i = blockIdx.x * 256 + threadIdx.x;   // 0..131071 vec8
    const bf16x8 z = {0,0,0,0,0,0,0,0};
    *(bf16x8*)(Hp + (size_t)i * 8) = z;
}

// ---------------------------------------------------------------------------
// Row LayerNorm over D=256, one wave per row, 4 rows/block.
// ---------------------------------------------------------------------------
template<int ADD, int WF, int WB>
__global__ __launch_bounds__(256)
void ln_k(const float* __restrict__ X, const float* __restrict__ g,
          const float* __restrict__ bt, float* __restrict__ Yf,
          ushort* __restrict__ Yb)
{
    const int lane = threadIdx.x & 63;
    const int row  = (blockIdx.x << 2) + (threadIdx.x >> 6);
    const size_t base = (size_t)row * Dm + (lane << 2);
    float4 v = *reinterpret_cast<const float4*>(&X[base]);
    float s = v.x + v.y + v.z + v.w;
    #pragma unroll
    for (int o = 1; o < 64; o <<= 1) s += __shfl_xor(s, o);
    const float mu = s * (1.0f / 256.0f);
    const float d0 = v.x - mu, d1 = v.y - mu, d2 = v.z - mu, d3 = v.w - mu;
    float q = d0*d0 + d1*d1 + d2*d2 + d3*d3;
    #pragma unroll
    for (int o = 1; o < 64; o <<= 1) q += __shfl_xor(q, o);
    const float rstd = rsqrtf(q * (1.0f / 256.0f) + 1e-5f);
    const int c = lane << 2;
    const float4 gg = *reinterpret_cast<const float4*>(&g[c]);
    const float4 bb = *reinterpret_cast<const float4*>(&bt[c]);
    float o0 = d0*rstd*gg.x + bb.x, o1 = d1*rstd*gg.y + bb.y;
    float o2 = d2*rstd*gg.z + bb.z, o3 = d3*rstd*gg.w + bb.w;
    if (ADD) {
        const float4 y = *reinterpret_cast<const float4*>(&Yf[base]);
        o0 += y.x; o1 += y.y; o2 += y.z; o3 += y.w;
    }
    if (WF) *reinterpret_cast<float4*>(&Yf[base]) = make_float4(o0, o1, o2, o3);
    if (WB) {
        ushort4 ub; ub.x = f2b(o0); ub.y = f2b(o1); ub.z = f2b(o2); ub.w = f2b(o3);
        *reinterpret_cast<ushort4*>(&Yb[base]) = ub;
    }
}

// ---------------------------------------------------------------------------
// Cross-attention core, bf16 in/out, fp32 math. One (b,h) per block.
// ---------------------------------------------------------------------------
__global__ __launch_bounds__(256)
void attn_k(const ushort* __restrict__ Q, const ushort* __restrict__ K,
            const ushort* __restrict__ V, ushort* __restrict__ O)
{
    __shared__ float Qs[32][33], Ks[32][33], Vs[32][33], Ss[32][33];
    const int bh = blockIdx.x;
    const int b = bh >> 3, h = bh & 7;
    const int tid = threadIdx.x;
    const int r  = tid >> 3;
    const int c4 = (tid & 7) << 2;
    const size_t base = ((size_t)b * Lseq + r) * Dm + h * 32 + c4;
    {
        const ushort4 q = *reinterpret_cast<const ushort4*>(&Q[base]);
        Qs[r][c4+0]=b2f(q.x); Qs[r][c4+1]=b2f(q.y); Qs[r][c4+2]=b2f(q.z); Qs[r][c4+3]=b2f(q.w);
        const ushort4 k = *reinterpret_cast<const ushort4*>(&K[base]);
        Ks[r][c4+0]=b2f(k.x); Ks[r][c4+1]=b2f(k.y); Ks[r][c4+2]=b2f(k.z); Ks[r][c4+3]=b2f(k.w);
        const ushort4 v = *reinterpret_cast<const ushort4*>(&V[base]);
        Vs[r][c4+0]=b2f(v.x); Vs[r][c4+1]=b2f(v.y); Vs[r][c4+2]=b2f(v.z); Vs[r][c4+3]=b2f(v.w);
    }
    __syncthreads();
    float sc[4] = {0.f, 0.f, 0.f, 0.f};
    #pragma unroll
    for (int d = 0; d < 32; ++d) {
        const float qv = Qs[r][d];
        #pragma unroll
        for (int j = 0; j < 4; ++j) sc[j] = fmaf(qv, Ks[c4+j][d], sc[j]);
    }
    #pragma unroll
    for (int j = 0; j < 4; ++j) sc[j] *= 0.17677669529663687f;
    float mx = fmaxf(fmaxf(sc[0], sc[1]), fmaxf(sc[2], sc[3]));
    #pragma unroll
    for (int o = 1; o < 8; o <<= 1) mx = fmaxf(mx, __shfl_xor(mx, o));
    float sum = 0.f;
    #pragma unroll
    for (int j = 0; j < 4; ++j) { sc[j] = expf(sc[j] - mx); sum += sc[j]; }
    #pragma unroll
    for (int o = 1; o < 8; o <<= 1) sum += __shfl_xor(sum, o);
    const float inv = 1.0f / sum;
    #pragma unroll
    for (int j = 0; j < 4; ++j) Ss[r][c4+j] = sc[j] * inv;
    __syncthreads();
    float o4[4] = {0.f, 0.f, 0.f, 0.f};
    #pragma unroll
    for (int k = 0; k < 32; ++k) {
        const float wv = Ss[r][k];
        #pragma unroll
        for (int j = 0; j < 4; ++j) o4[j] = fmaf(wv, Vs[k][c4+j], o4[j]);
    }
    ushort4 ob; ob.x=f2b(o4[0]); ob.y=f2b(o4[1]); ob.z=f2b(o4[2]); ob.w=f2b(o4[3]);
    *reinterpret_cast<ushort4*>(&O[base]) = ob;
}

// ---------------------------------------------------------------------------
// W_scpad[i][m][s] = sum_d sw[i][m][d] * C[i][d][s], bf16, s in [16,32) = 0.
// ---------------------------------------------------------------------------
__global__ __launch_bounds__(256)
void wsc_k(const float* __restrict__ sw, const float* __restrict__ Cc,
           ushort* __restrict__ Wp)
{
    const int i = blockIdx.x >> 4;
    const int m = ((blockIdx.x & 15) << 4) + (threadIdx.x >> 4);
    const int s = threadIdx.x & 15;
    const float* swr = sw + ((size_t)i << 16) + (m << 8);
    const float* cc  = Cc + ((size_t)i << 12) + s;
    float acc = 0.0f;
    #pragma unroll 8
    for (int d = 0; d < 256; ++d) acc = fmaf(swr[d], cc[d << 4], acc);
    ushort* o = Wp + ((size_t)i << 13) + (m << 5);
    o[s] = f2b(acc);
    o[s + 16] = 0;
}

__global__ __launch_bounds__(256)
void meanL_k(const float* __restrict__ X, float* __restrict__ G)
{
    const int idx = blockIdx.x * 256 + threadIdx.x;
    const int b = idx >> 8, d = idx & 255;
    const float* xp = X + (size_t)b * (Lseq * Dm) + d;
    float s = 0.0f;
    #pragma unroll
    for (int t = 0; t < Lseq; ++t) s += xp[t << 8];
    G[idx] = s * (1.0f / 32.0f);
}

__global__ __launch_bounds__(256)
void fillw_k(float* __restrict__ out)
{
    const int i = blockIdx.x * 256 + threadIdx.x;
    const float wm = 1.0f / 32.0f;
    out[i] = wm / (wm + wm + 1e-6f);
}

__global__ __launch_bounds__(256)
void cast_k(const float* __restrict__ src, ushort* __restrict__ dst, int n4)
{
    const int i = blockIdx.x * 256 + threadIdx.x;
    if (i < n4) {
        const float4 v = reinterpret_cast<const float4*>(src)[i];
        ushort4 o; o.x = f2b(v.x); o.y = f2b(v.y); o.z = f2b(v.z); o.w = f2b(v.w);
        reinterpret_cast<ushort4*>(dst)[i] = o;
    }
}

__global__ __launch_bounds__(256)
void cast_inw_k(const float* __restrict__ src, ushort* __restrict__ dst)
{
    const int i = blockIdx.x * 256 + threadIdx.x;
    const int blk = i >> 14, rem = i & 16383;
    const float4 v = reinterpret_cast<const float4*>(
        src + (size_t)blk * 131072 + 65536)[rem];
    ushort4 o; o.x = f2b(v.x); o.y = f2b(v.y); o.z = f2b(v.z); o.w = f2b(v.w);
    reinterpret_cast<ushort4*>(dst)[i] = o;
}

extern "C" void kernel_launch(void* const* d_in, const int* in_sizes, int n_in,
                              void* d_out, int out_size, void* d_ws, size_t ws_size,
                              hipStream_t stream)
{
    const float* ble_f   = (const float*)d_in[0];
    const float* vis_f   = (const float*)d_in[1];
    const float* bp_w    = (const float*)d_in[2];
    const float* bp_b    = (const float*)d_in[3];
    const float* bp_emb  = (const float*)d_in[4];
    const float* bp_g    = (const float*)d_in[5];
    const float* bp_beta = (const float*)d_in[6];
    const float* vp_w    = (const float*)d_in[7];
    const float* vp_b    = (const float*)d_in[8];
    const float* vp_emb  = (const float*)d_in[9];
    const float* vp_g    = (const float*)d_in[10];
    const float* vp_beta = (const float*)d_in[11];
    const float* a_qw    = (const float*)d_in[12];
    const float* a_qb    = (const float*)d_in[13];
    const float* a_kw    = (const float*)d_in[14];
    const float* a_kb    = (const float*)d_in[15];
    const float* a_vw    = (const float*)d_in[16];
    const float* a_vb    = (const float*)d_in[17];
    const float* a_ow    = (const float*)d_in[18];
    const float* a_ob    = (const float*)d_in[19];
    const float* a_g     = (const float*)d_in[20];
    const float* a_beta  = (const float*)d_in[21];
    const float* m_ln1_g = (const float*)d_in[22];
    const float* m_ln1_b = (const float*)d_in[23];
    const float* m_in_w  = (const float*)d_in[24];
    const float* m_in_b  = (const float*)d_in[25];
    const float* m_A     = (const float*)d_in[26];
    const float* m_B     = (const float*)d_in[27];
    const float* m_C     = (const float*)d_in[28];
    const float* m_gw    = (const float*)d_in[29];
    const float* m_gb    = (const float*)d_in[30];
    const float* m_sw    = (const float*)d_in[31];
    const float* m_sb    = (const float*)d_in[32];
    const float* m_ln2_g = (const float*)d_in[33];
    const float* m_ln2_b = (const float*)d_in[34];
    const float* m_f1w   = (const float*)d_in[35];
    const float* m_f1b   = (const float*)d_in[36];
    const float* m_f2w   = (const float*)d_in[37];
    const float* m_f2b   = (const float*)d_in[38];
    const float* fin_g   = (const float*)d_in[39];
    const float* fin_beta= (const float*)d_in[40];
    const float* fin_w   = (const float*)d_in[41];
    const float* fin_b   = (const float*)d_in[42];

    float* out = (float*)d_out;
    float* ws  = (float*)d_ws;
    const size_t NDf = (size_t)NROW * Dm;   // 8.39M elements

    float* F_res = ws;
    float* F0 = ws + 1 * NDf;
    float* F1 = ws + 2 * NDf;
    float* F2 = ws + 3 * NDf;
    ushort* S0 = (ushort*)(ws + 4 * NDf);
    ushort* S1 = S0 + NDf;
    ushort* S2 = S1 + NDf;
    ushort* S3 = S2 + NDf;
    ushort* S4 = S3 + NDf;
    ushort* Wa = S4 + NDf;
    ushort* W_bp  = Wa;                   // 32768
    ushort* W_vp  = W_bp + 32768;         // 65536
    ushort* W_q   = W_vp + 65536;         // 2*65536
    ushort* W_k   = W_q + 131072;
    ushort* W_v   = W_k + 131072;
    ushort* W_o   = W_v + 131072;
    ushort* W_g   = W_o + 131072;         // 6*65536
    ushort* W_in  = W_g + 393216;
    ushort* W_f1  = W_in + 393216;        // 6*262144
    ushort* W_f2  = W_f1 + 1572864;
    ushort* W_fin = W_f2 + 1572864;       // 65536
    ushort* W_sc  = W_fin + 65536;        // 6*8192 (padded K=32)
    ushort* Hpad  = W_sc + 49152;         // 32768*32
    // Overlays in F2 (33.5 MB): inputs (pre-attention), scan matrices (post-attention)
    ushort* B_ble = (ushort*)F2;          // dead before F2's first fp32 use
    ushort* B_vis = B_ble + (size_t)NROW * 128;
    ushort* T_all = (ushort*)F2;          // 6*512*512, written AFTER attention
    ushort* W_bm  = T_all + 1572864;      // 6*4096
    ushort* XBuf  = W_bm + 24576;         // 32768*16

    const dim3 blk(256);
    auto cgrid = [](int n4) { return dim3((n4 + 255) / 256); };

    // ---- weight / input casts + sw@C fold ----
    cast_k<<<cgrid(1048576), blk, 0, stream>>>(ble_f, B_ble, 1048576);
    cast_k<<<cgrid(2097152), blk, 0, stream>>>(vis_f, B_vis, 2097152);
    cast_k<<<cgrid(8192),   blk, 0, stream>>>(bp_w, W_bp, 8192);
    cast_k<<<cgrid(16384),  blk, 0, stream>>>(vp_w, W_vp, 16384);
    cast_k<<<cgrid(32768),  blk, 0, stream>>>(a_qw, W_q, 32768);
    cast_k<<<cgrid(32768),  blk, 0, stream>>>(a_kw, W_k, 32768);
    cast_k<<<cgrid(32768),  blk, 0, stream>>>(a_vw, W_v, 32768);
    cast_k<<<cgrid(32768),  blk, 0, stream>>>(a_ow, W_o, 32768);
    cast_k<<<cgrid(98304),  blk, 0, stream>>>(m_gw, W_g, 98304);
    cast_k<<<cgrid(393216), blk, 0, stream>>>(m_f1w, W_f1, 393216);
    cast_k<<<cgrid(393216), blk, 0, stream>>>(m_f2w, W_f2, 393216);
    cast_k<<<cgrid(16384),  blk, 0, stream>>>(fin_w, W_fin, 16384);
    cast_inw_k<<<cgrid(98304), blk, 0, stream>>>(m_in_w, W_in);
    wsc_k<<<96, blk, 0, stream>>>(m_sw, m_C, W_sc);

    auto gg = [](int M, int N) { return dim3(M / 128, N / 128); };

    // ---- input projections + LN ----
    mgemm<0,0,false,false,0><<<gg(256, NROW), blk, 0, stream>>>(B_ble, W_bp, bp_b, bp_emb, nullptr, nullptr, F0, nullptr, 128, 256);
    ln_k<0,1,1><<<NROW/4, blk, 0, stream>>>(F0, bp_g, bp_beta, F0, S0);
    mgemm<0,0,false,false,0><<<gg(256, NROW), blk, 0, stream>>>(B_vis, W_vp, vp_b, vp_emb, nullptr, nullptr, F1, nullptr, 256, 256);
    ln_k<0,1,1><<<NROW/4, blk, 0, stream>>>(F1, vp_g, vp_beta, F1, S1);

    // ---- two cross-attentions ----
    for (int a = 0; a < 2; ++a) {
        const ushort* qin_b = (a == 0) ? S0 : S1;
        const ushort* kin_b = (a == 0) ? S1 : S0;
        const float*  qin_f = (a == 0) ? F0 : F1;
        const size_t wo = (size_t)a * 65536;
        const size_t bo = (size_t)a * 256;
        mgemm<0,0,false,true,0><<<gg(256, NROW), blk, 0, stream>>>(qin_b, W_q + wo, a_qb + bo, nullptr, nullptr, nullptr, nullptr, S4, 256, 256);
        mgemm<0,0,false,true,0><<<gg(256, NROW), blk, 0, stream>>>(kin_b, W_k + wo, a_kb + bo, nullptr, nullptr, nullptr, nullptr, S2, 256, 256);
        mgemm<0,0,false,true,0><<<gg(256, NROW), blk, 0, stream>>>(kin_b, W_v + wo, a_vb + bo, nullptr, nullptr, nullptr, nullptr, S3, 256, 256);
        attn_k<<<Bsz * 8, blk, 0, stream>>>(S4, S2, S3, S4);
        mgemm<0,2,false,false,0><<<gg(256, NROW), blk, 0, stream>>>(S4, W_o + wo, a_ob + bo, nullptr, qin_f, nullptr, F2, nullptr, 256, 256);
        if (a == 0) ln_k<0,1,0><<<NROW/4, blk, 0, stream>>>(F2, a_g + bo, a_beta + bo, F_res, nullptr);
        else        ln_k<1,1,0><<<NROW/4, blk, 0, stream>>>(F2, a_g + bo, a_beta + bo, F_res, nullptr);
    }

    // ---- scan matrices (overlay F2, which is now dead) ----
    powT_k<<<6, blk, 0, stream>>>(m_A, T_all);
    cast_k<<<cgrid(6144), blk, 0, stream>>>(m_B, W_bm, 6144);
    zeroH_k<<<512, blk, 0, stream>>>(Hpad);

    // ---- 6 mamba blocks ----
    for (int i = 0; i < 6; ++i) {
        ln_k<0,0,1><<<NROW/4, blk, 0, stream>>>(F_res, m_ln1_g + i*256, m_ln1_b + i*256, nullptr, S0);
        // gate = sigmoid(xn @ gw^T + gb) -> S3 (bf16)
        mgemm<1,0,false,true,0><<<gg(256, NROW), blk, 0, stream>>>(S0, W_g + (size_t)i*65536, m_gb + i*256, nullptr, nullptr, nullptr, nullptr, S3, 256, 256);
        // x_in = (xn @ inw2^T + inb2) * gate -> S2 (bf16)
        mgemm<0,3,false,true,0><<<gg(256, NROW), blk, 0, stream>>>(S0, W_in + (size_t)i*65536, m_in_b + (size_t)i*512 + 256, nullptr, nullptr, S3, nullptr, S2, 256, 256);
        // XB = x_in @ Bm^T  (N x 16)
        xb_gemm<<<NROW/128, blk, 0, stream>>>(S2, W_bm + (size_t)i*4096, XBuf);
        // H(1024x512) = XB(1024x512) @ T^T  -> Hpad(32768x32) via OMAP
        mgemm<0,0,false,true,1><<<gg(512, 1024), blk, 0, stream>>>(XBuf, T_all + (size_t)i*262144, nullptr, nullptr, nullptr, nullptr, nullptr, Hpad, 512, 512);
        // F_res += h @ (sw@C)^T + sb   (K=32)
        mgemm<0,0,true,false,0><<<gg(256, NROW), blk, 0, stream>>>(Hpad, W_sc + (size_t)i*8192, m_sb + i*256, nullptr, nullptr, nullptr, F_res, nullptr, 32, 256);
        // FFN
        ln_k<0,0,1><<<NROW/4, blk, 0, stream>>>(F_res, m_ln2_g + i*256, m_ln2_b + i*256, nullptr, S0);
        mgemm<2,0,false,true,0><<<gg(1024, NROW), blk, 0, stream>>>(S0, W_f1 + (size_t)i*262144, m_f1b + i*1024, nullptr, nullptr, nullptr, nullptr, S1, 256, 1024);
        mgemm<0,0,true,false,0><<<gg(256, NROW), blk, 0, stream>>>(S1, W_f2 + (size_t)i*262144, m_f2b + i*256, nullptr, nullptr, nullptr, F_res, nullptr, 1024, 256);
    }

    // ---- head ----
    meanL_k<<<(Bsz * Dm) / 256, blk, 0, stream>>>(F_res, F0);
    ln_k<0,0,1><<<Bsz/4, blk, 0, stream>>>(F0, fin_g, fin_beta, nullptr, S1);
    mgemm<2,0,false,false,0><<<gg(256, Bsz), blk, 0, stream>>>(S1, W_fin, fin_b, nullptr, nullptr, nullptr, out, nullptr, 256, 256);
    fillw_k<<<8, blk, 0, stream>>>(out + (size_t)Bsz * Dm);
}

// Round 5
// 1320.909 us; speedup vs baseline: 4.0864x; 1.0836x over previous
//
#include <hip/hip_runtime.h>
#include <hip/hip_bf16.h>
#include <math.h>

static constexpr int Bsz  = 1024;
static constexpr int Lseq = 32;
static constexpr int Dm   = 256;
static constexpr int NROW = Bsz * Lseq;   // 32768

typedef __attribute__((ext_vector_type(8))) short bf16x8;
typedef __attribute__((ext_vector_type(4))) float f32x4;

__device__ __forceinline__ float sigm_f(float x) {
    return 1.0f / (1.0f + __expf(-x));
}
__device__ __forceinline__ float gelu_f(float x) {
    // tanh-approx gelu via sigmoid: 0.5x(1+tanh(u)) = x*sigm(2u)
    const float u = x * (0.7978845608028654f + 0.0356774081f * x * x);
    return x * sigm_f(2.0f * u);
}
__device__ __forceinline__ float b2f(ushort u) {
    union { float f; uint v; } t; t.v = ((uint)u) << 16; return t.f;
}
__device__ __forceinline__ ushort f2b(float f) {
    union { float f; uint v; } t; t.f = f;
    const uint lsb = (t.v >> 16) & 1u;
    t.v += 0x7fffu + lsb;                 // round-to-nearest-even
    return (ushort)(t.v >> 16);
}

#define GLDS(gp, lp) __builtin_amdgcn_global_load_lds( \
    (const __attribute__((address_space(1))) void*)(gp), \
    (__attribute__((address_space(3))) void*)(lp), 16, 0, 0)

// ---------------------------------------------------------------------------
// bf16 MFMA GEMM (m97 structure), 128x128 tile, BK=32, 256 threads.
// ACT: 0 none, 1 sigm, 2 gelu (non-dual only).
// OMAP: 0 normal; 1 scan-H remap idx = row*1024 + (col>>4)*32 + (col&15).
// DUAL: 0 single; 1 gateIn: Cb = sigm(A@W+b1) * (A@W2+b2);
//       2 two outs: Cb = A@W+b1, Cb2 = A@W2+b2 (both bf16).
// ---------------------------------------------------------------------------
template<int ACT, bool OUTBF, int OMAP, int DUAL>
__global__ __launch_bounds__(256)
void mgemm(const ushort* __restrict__ X, const ushort* __restrict__ W,
           const ushort* __restrict__ W2,
           const float* __restrict__ b1, const float* __restrict__ b2,
           float* __restrict__ Cf, ushort* __restrict__ Cb,
           ushort* __restrict__ Cb2, int K, int M)
{
    __shared__ ushort As[128 * 32];
    __shared__ ushort Bs[128 * 32];
    __shared__ ushort Bs2[DUAL ? 128 * 32 : 8];
    const int tid = threadIdx.x;
    const int w = tid >> 6, l = tid & 63;
    const int n0 = blockIdx.y << 7;
    const int m0 = blockIdx.x << 7;

    const int ric  = l >> 2;
    const int slot = l & 3;
    const int rL0 = (w << 4) + ric;
    const int rL1 = rL0 + 64;
    const int sw0 = slot ^ ((rL0 >> 1) & 3);
    const int sw1 = slot ^ ((rL1 >> 1) & 3);
    const ushort* gA0 = X + (size_t)(n0 + rL0) * K + (sw0 << 3);
    const ushort* gA1 = X + (size_t)(n0 + rL1) * K + (sw1 << 3);
    const ushort* gB0 = W + (size_t)(m0 + rL0) * K + (sw0 << 3);
    const ushort* gB1 = W + (size_t)(m0 + rL1) * K + (sw1 << 3);
    const ushort* gC0 = nullptr; const ushort* gC1 = nullptr;
    if constexpr (DUAL) {
        gC0 = W2 + (size_t)(m0 + rL0) * K + (sw0 << 3);
        gC1 = W2 + (size_t)(m0 + rL1) * K + (sw1 << 3);
    }
    ushort* lA0 = As + ((size_t)w << 9);
    ushort* lA1 = As + ((size_t)(w + 4) << 9);
    ushort* lB0 = Bs + ((size_t)w << 9);
    ushort* lB1 = Bs + ((size_t)(w + 4) << 9);
    ushort* lC0 = Bs2 + ((size_t)w << 9);
    ushort* lC1 = Bs2 + ((size_t)(w + 4) << 9);

    const int wr = (w >> 1) & 1, wc = w & 1;
    const int cl = l & 15, kg = l >> 4;
    int aoff[4], boff[4];
    #pragma unroll
    for (int m = 0; m < 4; ++m) {
        const int r = wr * 64 + m * 16 + cl;
        aoff[m] = r * 32 + ((kg ^ ((r >> 1) & 3)) << 3);
    }
    #pragma unroll
    for (int n = 0; n < 4; ++n) {
        const int r = wc * 64 + n * 16 + cl;
        boff[n] = r * 32 + ((kg ^ ((r >> 1) & 3)) << 3);
    }

    f32x4 acc[4][4];
    f32x4 acc2[DUAL ? 4 : 1][DUAL ? 4 : 1];
    #pragma unroll
    for (int m = 0; m < 4; ++m)
        #pragma unroll
        for (int n = 0; n < 4; ++n) {
            acc[m][n] = (f32x4){0.f, 0.f, 0.f, 0.f};
            if constexpr (DUAL) acc2[m][n] = (f32x4){0.f, 0.f, 0.f, 0.f};
        }

    for (int kc = 0; kc < K; kc += 32) {
        GLDS(gA0, lA0); GLDS(gA1, lA1);
        GLDS(gB0, lB0); GLDS(gB1, lB1);
        gA0 += 32; gA1 += 32; gB0 += 32; gB1 += 32;
        if constexpr (DUAL) {
            GLDS(gC0, lC0); GLDS(gC1, lC1);
            gC0 += 32; gC1 += 32;
        }
        __syncthreads();
        bf16x8 av[4], bv[4];
        #pragma unroll
        for (int m = 0; m < 4; ++m) av[m] = *(const bf16x8*)(As + aoff[m]);
        #pragma unroll
        for (int n = 0; n < 4; ++n) bv[n] = *(const bf16x8*)(Bs + boff[n]);
        #pragma unroll
        for (int m = 0; m < 4; ++m)
            #pragma unroll
            for (int n = 0; n < 4; ++n)
                acc[m][n] = __builtin_amdgcn_mfma_f32_16x16x32_bf16(
                    av[m], bv[n], acc[m][n], 0, 0, 0);
        if constexpr (DUAL) {
            bf16x8 cv[4];
            #pragma unroll
            for (int n = 0; n < 4; ++n) cv[n] = *(const bf16x8*)(Bs2 + boff[n]);
            #pragma unroll
            for (int m = 0; m < 4; ++m)
                #pragma unroll
                for (int n = 0; n < 4; ++n)
                    acc2[m][n] = __builtin_amdgcn_mfma_f32_16x16x32_bf16(
                        av[m], cv[n], acc2[m][n], 0, 0, 0);
        }
        __syncthreads();
    }

    const int colb = m0 + wc * 64 + cl;
    const int rowb = n0 + wr * 64 + (kg << 2);
    float biasA[4], biasB[4];
    #pragma unroll
    for (int n = 0; n < 4; ++n) {
        biasA[n] = (b1 != nullptr) ? b1[colb + n * 16] : 0.0f;
        if constexpr (DUAL) biasB[n] = b2[colb + n * 16];
    }
    #pragma unroll
    for (int m = 0; m < 4; ++m) {
        #pragma unroll
        for (int j = 0; j < 4; ++j) {
            const size_t row = (size_t)(rowb + m * 16 + j);
            #pragma unroll
            for (int n = 0; n < 4; ++n) {
                const int col = colb + n * 16;
                size_t idx;
                if (OMAP == 1) idx = row * 1024 + ((size_t)(col >> 4) << 5) + (col & 15);
                else           idx = row * (size_t)M + col;
                const float vA = acc[m][n][j] + biasA[n];
                if constexpr (DUAL == 1) {
                    const float vB = acc2[m][n][j] + biasB[n];
                    Cb[idx] = f2b(sigm_f(vA) * vB);
                } else if constexpr (DUAL == 2) {
                    Cb[idx]  = f2b(vA);
                    Cb2[idx] = f2b(acc2[m][n][j] + biasB[n]);
                } else {
                    float v = vA;
                    if (ACT == 1) v = sigm_f(v);
                    else if (ACT == 2) v = gelu_f(v);
                    if (OUTBF) Cb[idx] = f2b(v);
                    else       Cf[idx] = v;
                }
            }
        }
    }
}

// ---------------------------------------------------------------------------
// Full-row GEMM (64 rows x 256 cols/block, 256 thr, wave=16 rows) with fused
// residual + LayerNorm epilogue. v = X@W^T + b1 (+b2) (+E) (+Fres).
// WRV: Fres = v. LNOUT: 0 none; 1 Yb=LN(v); 2 Fres=LN(v); 3 both; 4 Fres+=LN(v).
// ---------------------------------------------------------------------------
template<bool ADD_E, bool ACC_F, bool WRV, int LNOUT, bool HASB2>
__global__ __launch_bounds__(256)
void growln_k(const ushort* __restrict__ X, const ushort* __restrict__ W,
              const float* __restrict__ b1, const float* __restrict__ b2,
              const float* __restrict__ E, const float* __restrict__ g,
              const float* __restrict__ bt, float* __restrict__ Fres,
              ushort* __restrict__ Yb, int K)
{
    __shared__ ushort As[64 * 32];     // 4 KB
    __shared__ ushort Bs[256 * 32];    // 16 KB
    const int tid = threadIdx.x;
    const int w = tid >> 6, l = tid & 63;
    const int n0 = blockIdx.x << 6;

    const int ric = l >> 2, slot = l & 3;
    const int rA  = (w << 4) + ric;
    const int swA = slot ^ ((rA >> 1) & 3);
    const ushort* gA = X + (size_t)(n0 + rA) * K + (swA << 3);
    ushort* lA = As + (w << 9);
    const int rB0 = (w << 4) + ric;
    const int rB1 = rB0 + 64, rB2 = rB0 + 128, rB3 = rB0 + 192;
    const ushort* gB0 = W + (size_t)rB0 * K + ((slot ^ ((rB0 >> 1) & 3)) << 3);
    const ushort* gB1 = W + (size_t)rB1 * K + ((slot ^ ((rB1 >> 1) & 3)) << 3);
    const ushort* gB2 = W + (size_t)rB2 * K + ((slot ^ ((rB2 >> 1) & 3)) << 3);
    const ushort* gB3 = W + (size_t)rB3 * K + ((slot ^ ((rB3 >> 1) & 3)) << 3);
    ushort* lB0 = Bs + (w << 9);
    ushort* lB1 = Bs + ((4 + w) << 9);
    ushort* lB2 = Bs + ((8 + w) << 9);
    ushort* lB3 = Bs + ((12 + w) << 9);

    const int cl = l & 15, kg = l >> 4;
    const int ar = (w << 4) + cl;
    const int aoff = ar * 32 + ((kg ^ ((ar >> 1) & 3)) << 3);
    int boff[16];
    #pragma unroll
    for (int n = 0; n < 16; ++n) {
        const int br = n * 16 + cl;
        boff[n] = br * 32 + ((kg ^ ((br >> 1) & 3)) << 3);
    }

    f32x4 acc[16];
    #pragma unroll
    for (int n = 0; n < 16; ++n) acc[n] = (f32x4){0.f, 0.f, 0.f, 0.f};

    for (int kc = 0; kc < K; kc += 32) {
        GLDS(gA, lA);   gA  += 32;
        GLDS(gB0, lB0); gB0 += 32;
        GLDS(gB1, lB1); gB1 += 32;
        GLDS(gB2, lB2); gB2 += 32;
        GLDS(gB3, lB3); gB3 += 32;
        __syncthreads();
        const bf16x8 av = *(const bf16x8*)(As + aoff);
        #pragma unroll
        for (int n = 0; n < 16; ++n) {
            const bf16x8 bv = *(const bf16x8*)(Bs + boff[n]);
            acc[n] = __builtin_amdgcn_mfma_f32_16x16x32_bf16(av, bv, acc[n], 0, 0, 0);
        }
        __syncthreads();
    }

    float bA[16];
    #pragma unroll
    for (int n = 0; n < 16; ++n) {
        float v = (b1 != nullptr) ? b1[n * 16 + cl] : 0.0f;
        if (HASB2) v += b2[n * 16 + cl];
        bA[n] = v;
    }
    float gg[16], bb[16];
    if (LNOUT > 0) {
        #pragma unroll
        for (int n = 0; n < 16; ++n) { gg[n] = g[n * 16 + cl]; bb[n] = bt[n * 16 + cl]; }
    }

    #pragma unroll
    for (int j = 0; j < 4; ++j) {
        const int r = n0 + (w << 4) + (kg << 2) + j;
        const size_t rb = (size_t)r << 8;
        float v[16];
        float s = 0.0f;
        #pragma unroll
        for (int n = 0; n < 16; ++n) {
            float x = acc[n][j] + bA[n];
            if (ADD_E) x += E[rb + n * 16 + cl];
            if (ACC_F) x += Fres[rb + n * 16 + cl];
            v[n] = x; s += x;
        }
        if (WRV) {
            #pragma unroll
            for (int n = 0; n < 16; ++n) Fres[rb + n * 16 + cl] = v[n];
        }
        if (LNOUT > 0) {
            #pragma unroll
            for (int o = 1; o < 16; o <<= 1) s += __shfl_xor(s, o);
            const float mu = s * (1.0f / 256.0f);
            float q = 0.0f;
            #pragma unroll
            for (int n = 0; n < 16; ++n) { const float d = v[n] - mu; q += d * d; }
            #pragma unroll
            for (int o = 1; o < 16; o <<= 1) q += __shfl_xor(q, o);
            const float rstd = rsqrtf(q * (1.0f / 256.0f) + 1e-5f);
            #pragma unroll
            for (int n = 0; n < 16; ++n) {
                const float y = (v[n] - mu) * rstd * gg[n] + bb[n];
                const size_t idx = rb + n * 16 + cl;
                if (LNOUT & 1) Yb[idx] = f2b(y);
                if (LNOUT == 2 || LNOUT == 3) Fres[idx] = y;
                if (LNOUT == 4) Fres[idx] += y;
            }
        }
    }
}

// ---------------------------------------------------------------------------
// Row LayerNorm (standalone; only 2 uses left). One wave/row, 4 rows/block.
// ---------------------------------------------------------------------------
__global__ __launch_bounds__(256)
void ln_k(const float* __restrict__ X, const float* __restrict__ g,
          const float* __restrict__ bt, ushort* __restrict__ Yb)
{
    const int lane = threadIdx.x & 63;
    const int row  = (blockIdx.x << 2) + (threadIdx.x >> 6);
    const size_t base = (size_t)row * Dm + (lane << 2);
    float4 v = *reinterpret_cast<const float4*>(&X[base]);
    float s = v.x + v.y + v.z + v.w;
    #pragma unroll
    for (int o = 1; o < 64; o <<= 1) s += __shfl_xor(s, o);
    const float mu = s * (1.0f / 256.0f);
    const float d0 = v.x - mu, d1 = v.y - mu, d2 = v.z - mu, d3 = v.w - mu;
    float q = d0*d0 + d1*d1 + d2*d2 + d3*d3;
    #pragma unroll
    for (int o = 1; o < 64; o <<= 1) q += __shfl_xor(q, o);
    const float rstd = rsqrtf(q * (1.0f / 256.0f) + 1e-5f);
    const int c = lane << 2;
    const float4 gg = *reinterpret_cast<const float4*>(&g[c]);
    const float4 bb = *reinterpret_cast<const float4*>(&bt[c]);
    ushort4 ub;
    ub.x = f2b(d0*rstd*gg.x + bb.x); ub.y = f2b(d1*rstd*gg.y + bb.y);
    ub.z = f2b(d2*rstd*gg.z + bb.z); ub.w = f2b(d3*rstd*gg.w + bb.w);
    *reinterpret_cast<ushort4*>(&Yb[base]) = ub;
}

// ---------------------------------------------------------------------------
// Cross-attention core, bf16 in/out, fp32 math. One (b,h) per block.
// ---------------------------------------------------------------------------
__global__ __launch_bounds__(256)
void attn_k(const ushort* __restrict__ Q, const ushort* __restrict__ K,
            const ushort* __restrict__ V, ushort* __restrict__ O)
{
    __shared__ float Qs[32][33], Ks[32][33], Vs[32][33], Ss[32][33];
    const int bh = blockIdx.x;
    const int b = bh >> 3, h = bh & 7;
    const int tid = threadIdx.x;
    const int r  = tid >> 3;
    const int c4 = (tid & 7) << 2;
    const size_t base = ((size_t)b * Lseq + r) * Dm + h * 32 + c4;
    {
        const ushort4 q = *reinterpret_cast<const ushort4*>(&Q[base]);
        Qs[r][c4+0]=b2f(q.x); Qs[r][c4+1]=b2f(q.y); Qs[r][c4+2]=b2f(q.z); Qs[r][c4+3]=b2f(q.w);
        const ushort4 k = *reinterpret_cast<const ushort4*>(&K[base]);
        Ks[r][c4+0]=b2f(k.x); Ks[r][c4+1]=b2f(k.y); Ks[r][c4+2]=b2f(k.z); Ks[r][c4+3]=b2f(k.w);
        const ushort4 v = *reinterpret_cast<const ushort4*>(&V[base]);
        Vs[r][c4+0]=b2f(v.x); Vs[r][c4+1]=b2f(v.y); Vs[r][c4+2]=b2f(v.z); Vs[r][c4+3]=b2f(v.w);
    }
    __syncthreads();
    float sc[4] = {0.f, 0.f, 0.f, 0.f};
    #pragma unroll
    for (int d = 0; d < 32; ++d) {
        const float qv = Qs[r][d];
        #pragma unroll
        for (int j = 0; j < 4; ++j) sc[j] = fmaf(qv, Ks[c4+j][d], sc[j]);
    }
    #pragma unroll
    for (int j = 0; j < 4; ++j) sc[j] *= 0.17677669529663687f;
    float mx = fmaxf(fmaxf(sc[0], sc[1]), fmaxf(sc[2], sc[3]));
    #pragma unroll
    for (int o = 1; o < 8; o <<= 1) mx = fmaxf(mx, __shfl_xor(mx, o));
    float sum = 0.f;
    #pragma unroll
    for (int j = 0; j < 4; ++j) { sc[j] = __expf(sc[j] - mx); sum += sc[j]; }
    #pragma unroll
    for (int o = 1; o < 8; o <<= 1) sum += __shfl_xor(sum, o);
    const float inv = 1.0f / sum;
    #pragma unroll
    for (int j = 0; j < 4; ++j) Ss[r][c4+j] = sc[j] * inv;
    __syncthreads();
    float o4[4] = {0.f, 0.f, 0.f, 0.f};
    #pragma unroll
    for (int k = 0; k < 32; ++k) {
        const float wv = Ss[r][k];
        #pragma unroll
        for (int j = 0; j < 4; ++j) o4[j] = fmaf(wv, Vs[k][c4+j], o4[j]);
    }
    ushort4 ob; ob.x=f2b(o4[0]); ob.y=f2b(o4[1]); ob.z=f2b(o4[2]); ob.w=f2b(o4[3]);
    *reinterpret_cast<ushort4*>(&O[base]) = ob;
}

// ---------------------------------------------------------------------------
// XB GEMM: XB[n,s] = sum_d X[n,d] * Bw[s,d]   (N x 16, K=256, bf16 out)
// ---------------------------------------------------------------------------
__global__ __launch_bounds__(256)
void xb_gemm(const ushort* __restrict__ X, const ushort* __restrict__ Bw,
             ushort* __restrict__ XB)
{
    __shared__ ushort As[128 * 32];
    __shared__ ushort Bsf[16 * 256];
    const int tid = threadIdx.x;
    const int w = tid >> 6, l = tid & 63;
    const int n0 = blockIdx.x << 7;
    #pragma unroll
    for (int rep = 0; rep < 2; ++rep) {
        const int u = (rep << 8) + tid;
        const int r = u >> 5;
        const int c8 = (u & 31) << 3;
        const int di = (r * 256 + c8) ^ ((r & 7) << 3);
        *(bf16x8*)(Bsf + di) = *(const bf16x8*)(Bw + r * 256 + c8);
    }
    const int ric = l >> 2, slot = l & 3;
    const int rL0 = (w << 4) + ric, rL1 = rL0 + 64;
    const int sw0 = slot ^ ((rL0 >> 1) & 3), sw1 = slot ^ ((rL1 >> 1) & 3);
    const ushort* gA0 = X + (size_t)(n0 + rL0) * 256 + (sw0 << 3);
    const ushort* gA1 = X + (size_t)(n0 + rL1) * 256 + (sw1 << 3);
    ushort* lA0 = As + (w << 9);
    ushort* lA1 = As + ((w + 4) << 9);
    const int cl = l & 15, kg = l >> 4;
    int aoff[2];
    #pragma unroll
    for (int m = 0; m < 2; ++m) {
        const int r = w * 32 + m * 16 + cl;
        aoff[m] = r * 32 + ((kg ^ ((r >> 1) & 3)) << 3);
    }
    f32x4 acc[2] = {(f32x4){0.f,0.f,0.f,0.f}, (f32x4){0.f,0.f,0.f,0.f}};
    for (int kc = 0; kc < 256; kc += 32) {
        GLDS(gA0, lA0); GLDS(gA1, lA1);
        gA0 += 32; gA1 += 32;
        __syncthreads();
        const bf16x8 av0 = *(const bf16x8*)(As + aoff[0]);
        const bf16x8 av1 = *(const bf16x8*)(As + aoff[1]);
        const int bidx = (cl * 256 + kc + (kg << 3)) ^ ((cl & 7) << 3);
        const bf16x8 bv = *(const bf16x8*)(Bsf + bidx);
        acc[0] = __builtin_amdgcn_mfma_f32_16x16x32_bf16(av0, bv, acc[0], 0, 0, 0);
        acc[1] = __builtin_amdgcn_mfma_f32_16x16x32_bf16(av1, bv, acc[1], 0, 0, 0);
        __syncthreads();
    }
    #pragma unroll
    for (int m = 0; m < 2; ++m)
        #pragma unroll
        for (int j = 0; j < 4; ++j) {
            const int row = n0 + w * 32 + m * 16 + (kg << 2) + j;
            XB[(size_t)row * 16 + cl] = f2b(acc[m][j]);
        }
}

// ---------------------------------------------------------------------------
// powT: T[t*16+s'][tau*16+s] = (A^(t-tau))[s'][s] for t>=tau else 0.
// ---------------------------------------------------------------------------
__global__ __launch_bounds__(256)
void powT_k(const float* __restrict__ A_all, ushort* __restrict__ T_all)
{
    __shared__ float P[2][16][16];
    __shared__ float Asm[16][16];
    const int layer = blockIdx.x;
    const float* A = A_all + layer * 256;
    ushort* T = T_all + (size_t)layer * 262144;
    const int tid = threadIdx.x;
    const int i = tid >> 4, j = tid & 15;
    Asm[i][j] = A[tid];
    const bf16x8 z = {0,0,0,0,0,0,0,0};
    for (int u = tid; u < 32768; u += 256)
        *(bf16x8*)(T + (size_t)u * 8) = z;
    P[0][i][j] = (i == j) ? 1.0f : 0.0f;
    __syncthreads();
    for (int k = 0; k < 32; ++k) {
        const float pv = P[k & 1][i][j];
        const ushort pb = f2b(pv);
        for (int tau = 0; tau + k < 32; ++tau)
            T[(size_t)((tau + k) * 16 + i) * 512 + tau * 16 + j] = pb;
        float acc = 0.0f;
        #pragma unroll
        for (int l2 = 0; l2 < 16; ++l2) acc = fmaf(P[k & 1][i][l2], Asm[l2][j], acc);
        P[(k & 1) ^ 1][i][j] = acc;
        __syncthreads();
    }
}

__global__ __launch_bounds__(256)
void zeroH_k(ushort* __restrict__ Hp)
{
    const int i = blockIdx.x * 256 + threadIdx.x;
    const bf16x8 z = {0,0,0,0,0,0,0,0};
    *(bf16x8*)(Hp + (size_t)i * 8) = z;
}

__global__ __launch_bounds__(256)
void wsc_k(const float* __restrict__ sw, const float* __restrict__ Cc,
           ushort* __restrict__ Wp)
{
    const int i = blockIdx.x >> 4;
    const int m = ((blockIdx.x & 15) << 4) + (threadIdx.x >> 4);
    const int s = threadIdx.x & 15;
    const float* swr = sw + ((size_t)i << 16) + (m << 8);
    const float* cc  = Cc + ((size_t)i << 12) + s;
    float acc = 0.0f;
    #pragma unroll 8
    for (int d = 0; d < 256; ++d) acc = fmaf(swr[d], cc[d << 4], acc);
    ushort* o = Wp + ((size_t)i << 13) + (m << 5);
    o[s] = f2b(acc);
    o[s + 16] = 0;
}

__global__ __launch_bounds__(256)
void meanL_k(const float* __restrict__ X, float* __restrict__ G)
{
    const int idx = blockIdx.x * 256 + threadIdx.x;
    const int b = idx >> 8, d = idx & 255;
    const float* xp = X + (size_t)b * (Lseq * Dm) + d;
    float s = 0.0f;
    #pragma unroll
    for (int t = 0; t < Lseq; ++t) s += xp[t << 8];
    G[idx] = s * (1.0f / 32.0f);
}

__global__ __launch_bounds__(256)
void fillw_k(float* __restrict__ out)
{
    const int i = blockIdx.x * 256 + threadIdx.x;
    const float wm = 1.0f / 32.0f;
    out[i] = wm / (wm + wm + 1e-6f);
}

__global__ __launch_bounds__(256)
void cast_k(const float* __restrict__ src, ushort* __restrict__ dst, int n4)
{
    const int i = blockIdx.x * 256 + threadIdx.x;
    if (i < n4) {
        const float4 v = reinterpret_cast<const float4*>(src)[i];
        ushort4 o; o.x = f2b(v.x); o.y = f2b(v.y); o.z = f2b(v.z); o.w = f2b(v.w);
        reinterpret_cast<ushort4*>(dst)[i] = o;
    }
}

__global__ __launch_bounds__(256)
void cast_inw_k(const float* __restrict__ src, ushort* __restrict__ dst)
{
    const int i = blockIdx.x * 256 + threadIdx.x;
    const int blk = i >> 14, rem = i & 16383;
    const float4 v = reinterpret_cast<const float4*>(
        src + (size_t)blk * 131072 + 65536)[rem];
    ushort4 o; o.x = f2b(v.x); o.y = f2b(v.y); o.z = f2b(v.z); o.w = f2b(v.w);
    reinterpret_cast<ushort4*>(dst)[i] = o;
}

extern "C" void kernel_launch(void* const* d_in, const int* in_sizes, int n_in,
                              void* d_out, int out_size, void* d_ws, size_t ws_size,
                              hipStream_t stream)
{
    const float* ble_f   = (const float*)d_in[0];
    const float* vis_f   = (const float*)d_in[1];
    const float* bp_w    = (const float*)d_in[2];
    const float* bp_b    = (const float*)d_in[3];
    const float* bp_emb  = (const float*)d_in[4];
    const float* bp_g    = (const float*)d_in[5];
    const float* bp_beta = (const float*)d_in[6];
    const float* vp_w    = (const float*)d_in[7];
    const float* vp_b    = (const float*)d_in[8];
    const float* vp_emb  = (const float*)d_in[9];
    const float* vp_g    = (const float*)d_in[10];
    const float* vp_beta = (const float*)d_in[11];
    const float* a_qw    = (const float*)d_in[12];
    const float* a_qb    = (const float*)d_in[13];
    const float* a_kw    = (const float*)d_in[14];
    const float* a_kb    = (const float*)d_in[15];
    const float* a_vw    = (const float*)d_in[16];
    const float* a_vb    = (const float*)d_in[17];
    const float* a_ow    = (const float*)d_in[18];
    const float* a_ob    = (const float*)d_in[19];
    const float* a_g     = (const float*)d_in[20];
    const float* a_beta  = (const float*)d_in[21];
    const float* m_ln1_g = (const float*)d_in[22];
    const float* m_ln1_b = (const float*)d_in[23];
    const float* m_in_w  = (const float*)d_in[24];
    const float* m_in_b  = (const float*)d_in[25];
    const float* m_A     = (const float*)d_in[26];
    const float* m_B     = (const float*)d_in[27];
    const float* m_C     = (const float*)d_in[28];
    const float* m_gw    = (const float*)d_in[29];
    const float* m_gb    = (const float*)d_in[30];
    const float* m_sw    = (const float*)d_in[31];
    const float* m_sb    = (const float*)d_in[32];
    const float* m_ln2_g = (const float*)d_in[33];
    const float* m_ln2_b = (const float*)d_in[34];
    const float* m_f1w   = (const float*)d_in[35];
    const float* m_f1b   = (const float*)d_in[36];
    const float* m_f2w   = (const float*)d_in[37];
    const float* m_f2b   = (const float*)d_in[38];
    const float* fin_g   = (const float*)d_in[39];
    const float* fin_beta= (const float*)d_in[40];
    const float* fin_w   = (const float*)d_in[41];
    const float* fin_b   = (const float*)d_in[42];

    float* out = (float*)d_out;
    float* ws  = (float*)d_ws;
    const size_t NDf = (size_t)NROW * Dm;

    float* F_res = ws;
    float* F0 = ws + 1 * NDf;
    float* F1 = ws + 2 * NDf;
    float* F2 = ws + 3 * NDf;          // overlay arena only (no fp32 use)
    ushort* S0 = (ushort*)(ws + 4 * NDf);
    ushort* S1 = S0 + NDf;
    ushort* S2 = S1 + NDf;
    ushort* S3 = S2 + NDf;
    ushort* S4 = S3 + NDf;
    ushort* Wa = S4 + NDf;
    ushort* W_bp  = Wa;                   // 32768
    ushort* W_vp  = W_bp + 32768;         // 65536
    ushort* W_q   = W_vp + 65536;         // 2*65536
    ushort* W_k   = W_q + 131072;
    ushort* W_v   = W_k + 131072;
    ushort* W_o   = W_v + 131072;
    ushort* W_g   = W_o + 131072;         // 6*65536
    ushort* W_in  = W_g + 393216;
    ushort* W_f1  = W_in + 393216;        // 6*262144
    ushort* W_f2  = W_f1 + 1572864;
    ushort* W_fin = W_f2 + 1572864;       // 65536
    ushort* W_sc  = W_fin + 65536;        // 6*8192 (padded K=32)
    ushort* Hpad  = W_sc + 49152;         // 32768*32
    // Overlays in F2: inputs (pre-attention), scan matrices (post-attention)
    ushort* B_ble = (ushort*)F2;
    ushort* B_vis = B_ble + (size_t)NROW * 128;
    ushort* T_all = (ushort*)F2;          // 6*512*512, written AFTER attention
    ushort* W_bm  = T_all + 1572864;
    ushort* XBuf  = W_bm + 24576;         // 32768*16

    const dim3 blk(256);
    auto cgrid = [](int n4) { return dim3((n4 + 255) / 256); };

    // ---- weight / input casts + folds ----
    cast_k<<<cgrid(1048576), blk, 0, stream>>>(ble_f, B_ble, 1048576);
    cast_k<<<cgrid(2097152), blk, 0, stream>>>(vis_f, B_vis, 2097152);
    cast_k<<<cgrid(8192),   blk, 0, stream>>>(bp_w, W_bp, 8192);
    cast_k<<<cgrid(16384),  blk, 0, stream>>>(vp_w, W_vp, 16384);
    cast_k<<<cgrid(32768),  blk, 0, stream>>>(a_qw, W_q, 32768);
    cast_k<<<cgrid(32768),  blk, 0, stream>>>(a_kw, W_k, 32768);
    cast_k<<<cgrid(32768),  blk, 0, stream>>>(a_vw, W_v, 32768);
    cast_k<<<cgrid(32768),  blk, 0, stream>>>(a_ow, W_o, 32768);
    cast_k<<<cgrid(98304),  blk, 0, stream>>>(m_gw, W_g, 98304);
    cast_k<<<cgrid(393216), blk, 0, stream>>>(m_f1w, W_f1, 393216);
    cast_k<<<cgrid(393216), blk, 0, stream>>>(m_f2w, W_f2, 393216);
    cast_k<<<cgrid(16384),  blk, 0, stream>>>(fin_w, W_fin, 16384);
    cast_inw_k<<<cgrid(98304), blk, 0, stream>>>(m_in_w, W_in);
    wsc_k<<<96, blk, 0, stream>>>(m_sw, m_C, W_sc);

    auto gg = [](int M, int N) { return dim3(M / 128, N / 128); };
    const dim3 gRow(NROW / 64);

    // ---- input projections + fused LN ----
    growln_k<false,false,false,3,true><<<gRow, blk, 0, stream>>>(
        B_ble, W_bp, bp_b, bp_emb, nullptr, bp_g, bp_beta, F0, S0, 128);
    growln_k<false,false,false,3,true><<<gRow, blk, 0, stream>>>(
        B_vis, W_vp, vp_b, vp_emb, nullptr, vp_g, vp_beta, F1, S1, 256);

    // ---- two cross-attentions ----
    for (int a = 0; a < 2; ++a) {
        const ushort* qin_b = (a == 0) ? S0 : S1;
        const ushort* kin_b = (a == 0) ? S1 : S0;
        const float*  qin_f = (a == 0) ? F0 : F1;
        const size_t wo = (size_t)a * 65536;
        const size_t bo = (size_t)a * 256;
        mgemm<0,true,0,0><<<gg(256, NROW), blk, 0, stream>>>(
            qin_b, W_q + wo, nullptr, a_qb + bo, nullptr, nullptr, S4, nullptr, 256, 256);
        mgemm<0,true,0,2><<<gg(256, NROW), blk, 0, stream>>>(
            kin_b, W_k + wo, W_v + wo, a_kb + bo, a_vb + bo, nullptr, S2, S3, 256, 256);
        attn_k<<<Bsz * 8, blk, 0, stream>>>(S4, S2, S3, S4);
        if (a == 0)
            growln_k<true,false,false,2,false><<<gRow, blk, 0, stream>>>(
                S4, W_o + wo, a_ob + bo, nullptr, qin_f, a_g + bo, a_beta + bo, F_res, nullptr, 256);
        else
            growln_k<true,false,false,4,false><<<gRow, blk, 0, stream>>>(
                S4, W_o + wo, a_ob + bo, nullptr, qin_f, a_g + bo, a_beta + bo, F_res, nullptr, 256);
    }

    // ---- scan matrices (overlay F2, now dead) ----
    powT_k<<<6, blk, 0, stream>>>(m_A, T_all);
    cast_k<<<cgrid(6144), blk, 0, stream>>>(m_B, W_bm, 6144);
    zeroH_k<<<512, blk, 0, stream>>>(Hpad);

    // ln1 of block 0 (subsequent blocks get ln1 from f2's fused epilogue)
    ln_k<<<NROW/4, blk, 0, stream>>>(F_res, m_ln1_g, m_ln1_b, S0);

    // ---- 6 mamba blocks ----
    for (int i = 0; i < 6; ++i) {
        // x_in = sigm(S0@Wg+gb) * (S0@Win+inb) -> S2 (dual GEMM)
        mgemm<0,true,0,1><<<gg(256, NROW), blk, 0, stream>>>(
            S0, W_g + (size_t)i*65536, W_in + (size_t)i*65536,
            m_gb + i*256, m_in_b + (size_t)i*512 + 256, nullptr, S2, nullptr, 256, 256);
        xb_gemm<<<NROW/128, blk, 0, stream>>>(S2, W_bm + (size_t)i*4096, XBuf);
        mgemm<0,true,1,0><<<gg(512, 1024), blk, 0, stream>>>(
            XBuf, T_all + (size_t)i*262144, nullptr, nullptr, nullptr, nullptr, Hpad, nullptr, 512, 512);
        // F_res += H@(sw@C)^T + sb ; S0 = ln2(F_res)
        growln_k<false,true,true,1,false><<<gRow, blk, 0, stream>>>(
            Hpad, W_sc + (size_t)i*8192, m_sb + i*256, nullptr, nullptr,
            m_ln2_g + i*256, m_ln2_b + i*256, F_res, S0, 32);
        // S1 = gelu(S0@W1+b1)
        mgemm<2,true,0,0><<<gg(1024, NROW), blk, 0, stream>>>(
            S0, W_f1 + (size_t)i*262144, nullptr, m_f1b + i*1024, nullptr, nullptr, S1, nullptr, 256, 1024);
        // F_res += S1@W2+b2 ; S0 = ln1_{i+1}(F_res)  (skip LN for last block)
        if (i < 5)
            growln_k<false,true,true,1,false><<<gRow, blk, 0, stream>>>(
                S1, W_f2 + (size_t)i*262144, m_f2b + i*256, nullptr, nullptr,
                m_ln1_g + (i+1)*256, m_ln1_b + (i+1)*256, F_res, S0, 1024);
        else
            growln_k<false,true,true,0,false><<<gRow, blk, 0, stream>>>(
                S1, W_f2 + (size_t)i*262144, m_f2b + i*256, nullptr, nullptr,
                nullptr, nullptr, F_res, nullptr, 1024);
    }

    // ---- head ----
    meanL_k<<<(Bsz * Dm) / 256, blk, 0, stream>>>(F_res, F0);
    ln_k<<<Bsz/4, blk, 0, stream>>>(F0, fin_g, fin_beta, S1);
    mgemm<2,false,0,0><<<gg(256, Bsz), blk, 0, stream>>>(
        S1, W_fin, nullptr, fin_b, nullptr, out, nullptr, nullptr, 256, 256);
    fillw_k<<<8, blk, 0, stream>>>(out + (size_t)Bsz * Dm);
}